// Round 11
// baseline (8409.893 us; speedup 1.0000x reference)
//
#include <hip/hip_runtime.h>
#include <hip/hip_cooperative_groups.h>
#include <math.h>

namespace cg = cooperative_groups;

#define Bb 4096
#define Mm 306
#define Nn 984      // complex cols
#define NCP 1024    // padded complex cols
#define KA 2048     // w real k-cols (padded)
#define ITERS 50
#define KSQ 9       // squaring stages: G^(2^9) then Rayleigh

typedef _Float16 f16x8 __attribute__((ext_vector_type(8)));
typedef float f32x16 __attribute__((ext_vector_type(16)));

__device__ __forceinline__ void cmac(float2& c, const float2 a, const float2 b) {
    c.x = fmaf(a.x, b.x, c.x);
    c.x = fmaf(-a.y, b.y, c.x);
    c.y = fmaf(a.x, b.y, c.y);
    c.y = fmaf(a.y, b.x, c.y);
}

__device__ __forceinline__ unsigned short f16bits(float v) {
    union { _Float16 h; unsigned short u; } cv;
    cv.h = (_Float16)v;
    return cv.u;
}
__device__ __forceinline__ float f16lo(unsigned int u) {
    union { unsigned short s; _Float16 h; } cv; cv.s = (unsigned short)(u & 0xffffu);
    return (float)cv.h;
}
__device__ __forceinline__ float f16hi(unsigned int u) {
    union { unsigned short s; _Float16 h; } cv; cv.s = (unsigned short)(u >> 16);
    return (float)cv.h;
}

__device__ __forceinline__ void load_lds16(const void* g, void* l) {
    __builtin_amdgcn_global_load_lds((const __attribute__((address_space(1))) void*)g,
                                     (__attribute__((address_space(3))) void*)l, 16, 0, 0);
}

// ---- swizzled uint (4B) index, w/A operand (K=2048: 32 ktiles), (row b, complex col c) --
__device__ __forceinline__ size_t swzA(int b, int c) {
    return ((size_t)(((b >> 7) * 32 + (c >> 5)) * 1024 + ((c >> 2) & 7) * 128 + (b & 127))) * 4 + (c & 3);
}
// ---- B operand (Q op, K=2048: 32 ktiles), (row jr, uint col q) ----
__device__ __forceinline__ size_t swzB(int jr, int q) {
    return ((size_t)(((jr >> 7) * 32 + (q >> 5)) * 1024 + ((q >> 2) & 7) * 128 + (jr & 127))) * 4 + (q & 3);
}
// ---- A2 operand (r pack, K=640: 10 ktiles), (row b, complex col c<320) ----
__device__ __forceinline__ size_t swzA2(int b, int c) {
    return ((size_t)(((b >> 7) * 10 + (c >> 5)) * 1024 + ((c >> 2) & 7) * 128 + (b & 127))) * 4 + (c & 3);
}
// ---- B2 operand (-step*conj(phi) pack, K=640: 10 ktiles), (row jr, uint col q<320) ----
__device__ __forceinline__ size_t swzB2(int jr, int q) {
    return ((size_t)(((jr >> 7) * 10 + (q >> 5)) * 1024 + ((q >> 2) & 7) * 128 + (jr & 127))) * 4 + (q & 3);
}

// ---------------- G = phi * phi^H  (306x306 complex), tiled + split-K ----------------
__global__ void gram_kernel(const float* __restrict__ pr, const float* __restrict__ pi,
                            float2* __restrict__ G) {
    __shared__ float2 As[32][33];
    __shared__ float2 Bs[32][33];
    int tx = threadIdx.x, ty = threadIdx.y;
    int t = ty * 16 + tx;
    int i0 = blockIdx.y * 32, j0 = blockIdx.x * 32;
    int zs = blockIdx.z * 246;
    int ze = zs + 246 < Nn ? zs + 246 : Nn;
    float2 acc[2][2] = {};
    for (int k0 = zs; k0 < ze; k0 += 32) {
        #pragma unroll
        for (int rep = 0; rep < 4; ++rep) {
            int idx = t + rep * 256;
            int rr = idx >> 5, cc = idx & 31;
            int gk = k0 + cc;
            int gi = i0 + rr, gj = j0 + rr;
            float2 a = make_float2(0.f, 0.f), b = make_float2(0.f, 0.f);
            if (gk < ze) {
                if (gi < Mm) a = make_float2(pr[(size_t)gi * Nn + gk], pi[(size_t)gi * Nn + gk]);
                if (gj < Mm) b = make_float2(pr[(size_t)gj * Nn + gk], pi[(size_t)gj * Nn + gk]);
            }
            As[rr][cc] = a; Bs[rr][cc] = b;
        }
        __syncthreads();
        #pragma unroll 8
        for (int kk = 0; kk < 32; ++kk) {
            float2 a0 = As[ty * 2][kk], a1 = As[ty * 2 + 1][kk];
            float2 b0 = Bs[tx * 2][kk], b1 = Bs[tx * 2 + 1][kk];
            #define GMAC(qq, aa, bb) \
                qq.x = fmaf(aa.x, bb.x, qq.x); qq.x = fmaf(aa.y, bb.y, qq.x); \
                qq.y = fmaf(aa.y, bb.x, qq.y); qq.y = fmaf(-aa.x, bb.y, qq.y);
            GMAC(acc[0][0], a0, b0) GMAC(acc[0][1], a0, b1)
            GMAC(acc[1][0], a1, b0) GMAC(acc[1][1], a1, b1)
            #undef GMAC
        }
        __syncthreads();
    }
    #pragma unroll
    for (int i = 0; i < 2; ++i) {
        int gi = i0 + ty * 2 + i;
        #pragma unroll
        for (int j = 0; j < 2; ++j) {
            int gj = j0 + tx * 2 + j;
            if (gi < Mm && gj < Mm) {
                atomicAdd(&G[gi * Mm + gj].x, acc[i][j].x);
                atomicAdd(&G[gi * Mm + gj].y, acc[i][j].y);
            }
        }
    }
}

// ---------------- frobz: Frobenius^2 of src + zero dst (fused with next-stage memset) ----
__global__ void frobz_kernel(const float2* __restrict__ H, float* __restrict__ slot,
                             float2* __restrict__ dst, int n) {
    int idx = blockIdx.x * blockDim.x + threadIdx.x;
    int stride = gridDim.x * blockDim.x;
    float s = 0.f;
    for (int i = idx; i < n; i += stride) {
        float2 v = H[i];
        s = fmaf(v.x, v.x, s);
        s = fmaf(v.y, v.y, s);
        dst[i] = make_float2(0.f, 0.f);
    }
    #pragma unroll
    for (int o = 32; o > 0; o >>= 1) s += __shfl_down(s, o, 64);
    __shared__ float wsum[4];
    int lane = threadIdx.x & 63, wv = threadIdx.x >> 6;
    if (lane == 0) wsum[wv] = s;
    __syncthreads();
    if (threadIdx.x == 0) atomicAdd(slot, wsum[0] + wsum[1] + wsum[2] + wsum[3]);
}

// ---------------- C += (A/||A||_F)^2 partial (split-K, C pre-zeroed) ----------------
__global__ void sqmm_kernel(const float2* __restrict__ A, float2* __restrict__ C,
                            const float* __restrict__ fslot) {
    __shared__ float2 As[32][33];
    __shared__ float2 Bs[32][33];
    float inv = 1.0f / fslot[0];
    int tx = threadIdx.x, ty = threadIdx.y;
    int t = ty * 16 + tx;
    int r0 = blockIdx.y * 32, c0 = blockIdx.x * 32;
    int zs = blockIdx.z * 80;
    int ze = zs + 80 < Mm ? zs + 80 : Mm;
    float2 acc[2][2] = {};
    for (int k0 = zs; k0 < ze; k0 += 32) {
        #pragma unroll
        for (int i = 0; i < 4; ++i) {
            int idx = t + i * 256;
            int rr = idx >> 5, cc = idx & 31;
            int gr = r0 + rr, gk = k0 + cc;
            As[rr][cc] = (gr < Mm && gk < ze) ? A[gr * Mm + gk] : make_float2(0.f, 0.f);
            int gk2 = k0 + rr, gc = c0 + cc;
            Bs[rr][cc] = (gk2 < ze && gc < Mm) ? A[gk2 * Mm + gc] : make_float2(0.f, 0.f);
        }
        __syncthreads();
        #pragma unroll 8
        for (int kk = 0; kk < 32; ++kk) {
            float2 a0 = As[ty * 2][kk], a1 = As[ty * 2 + 1][kk];
            float2 b0 = Bs[kk][tx * 2], b1 = Bs[kk][tx * 2 + 1];
            cmac(acc[0][0], a0, b0); cmac(acc[0][1], a0, b1);
            cmac(acc[1][0], a1, b0); cmac(acc[1][1], a1, b1);
        }
        __syncthreads();
    }
    #pragma unroll
    for (int i = 0; i < 2; ++i) {
        int gr = r0 + ty * 2 + i;
        #pragma unroll
        for (int j = 0; j < 2; ++j) {
            int gc = c0 + tx * 2 + j;
            if (gr < Mm && gc < Mm) {
                atomicAdd(&C[gr * Mm + gc].x, acc[i][j].x * inv);
                atomicAdd(&C[gr * Mm + gc].y, acc[i][j].y * inv);
            }
        }
    }
}

// ---------------- Rayleigh, parallelized: ray1 v=H*ones; ray2 num/den; ray3 sc ----------
__global__ void ray1_kernel(const float2* __restrict__ H, float2* __restrict__ v) {
    int t = blockIdx.x;          // row 0..Mm-1
    int k = threadIdx.x;         // 256 threads
    float sx = 0.f, sy = 0.f;
    for (int j = k; j < Mm; j += 256) {
        float2 h = H[(size_t)t * Mm + j];
        sx += h.x; sy += h.y;
    }
    #pragma unroll
    for (int o = 32; o > 0; o >>= 1) { sx += __shfl_down(sx, o, 64); sy += __shfl_down(sy, o, 64); }
    __shared__ float wx[4], wy[4];
    int lane = k & 63, wv = k >> 6;
    if (lane == 0) { wx[wv] = sx; wy[wv] = sy; }
    __syncthreads();
    if (k == 0) v[t] = make_float2(wx[0] + wx[1] + wx[2] + wx[3],
                                   wy[0] + wy[1] + wy[2] + wy[3]);
}

__global__ void ray2_kernel(const float2* __restrict__ G, const float2* __restrict__ v,
                            float* __restrict__ slots) {
    int t = blockIdx.x;
    int k0 = threadIdx.x;
    float ux = 0.f, uy = 0.f;
    for (int k = k0; k < Mm; k += 256) {
        float2 g = G[(size_t)k * Mm + t];
        float2 vk = v[k];
        ux = fmaf(g.x, vk.x, ux); ux = fmaf(g.y, vk.y, ux);
        uy = fmaf(g.x, vk.y, uy); uy = fmaf(-g.y, vk.x, uy);
    }
    #pragma unroll
    for (int o = 32; o > 0; o >>= 1) { ux += __shfl_down(ux, o, 64); uy += __shfl_down(uy, o, 64); }
    __shared__ float wx[4], wy[4];
    int lane = k0 & 63, wv = k0 >> 6;
    if (lane == 0) { wx[wv] = ux; wy[wv] = uy; }
    __syncthreads();
    if (k0 == 0) {
        float sux = wx[0] + wx[1] + wx[2] + wx[3];
        float suy = wy[0] + wy[1] + wy[2] + wy[3];
        float2 vt = v[t];
        atomicAdd(&slots[16], vt.x * sux + vt.y * suy);   // num partial
        atomicAdd(&slots[17], vt.x * vt.x + vt.y * vt.y); // den partial
    }
}

__global__ void ray3_kernel(const float* __restrict__ slots, float* __restrict__ sc) {
    float step = slots[17] / slots[16];   // 1/lambda = den/num
    sc[0] = step;
    sc[1] = 0.1f * step;
}

// ---------------- qpack: M = I - step*Q, Hermitian-exploiting -----------------------
// Q[n][c] = sum_m phi[m][n]*conj(phi[m][c]); Q[c][n] = conj(Q[n][c]) exactly.
// Blocks entirely below the diagonal (all c < n) are skipped (~45% of grid); kept
// blocks write (n,c) for c >= n and mirror-write conj at (c,n) for c > n. Every
// entry written exactly once. 2x4 micro-tile, conflict-free Pc mapping (j*16+tx).
__global__ void qpack_kernel(const float* __restrict__ pr, const float* __restrict__ pi,
                             unsigned int* __restrict__ Bu, const float* __restrict__ sc) {
    __shared__ float2 Pn[16][33];
    __shared__ float2 Pc[16][65];
    int n0 = blockIdx.x * 32, c0 = blockIdx.y * 64;
    if (c0 + 64 <= n0) return;   // whole block has c < n: covered by mirror writes
    float nstep = -sc[0];
    int t = threadIdx.x;
    int tx = t & 15, ty = t >> 4;
    float2 q[2][4] = {};
    for (int m0 = 0; m0 < Mm; m0 += 16) {
        #pragma unroll
        for (int rep = 0; rep < 6; ++rep) {
            int idx = t + rep * 256;
            if (idx < 512) {
                int mm = idx >> 5, col = idx & 31;
                int gm = m0 + mm;
                float2 a = make_float2(0.f, 0.f);
                if (gm < Mm && n0 + col < Nn)
                    a = make_float2(pr[(size_t)gm * Nn + n0 + col], pi[(size_t)gm * Nn + n0 + col]);
                Pn[mm][col] = a;
            } else {
                int idx2 = idx - 512;
                int mm = idx2 >> 6, col = idx2 & 63;
                int gm = m0 + mm;
                float2 b = make_float2(0.f, 0.f);
                if (gm < Mm && c0 + col < Nn)
                    b = make_float2(pr[(size_t)gm * Nn + c0 + col], pi[(size_t)gm * Nn + c0 + col]);
                Pc[mm][col] = b;
            }
        }
        __syncthreads();
        #pragma unroll
        for (int mm = 0; mm < 16; ++mm) {
            float2 a0 = Pn[mm][ty * 2], a1 = Pn[mm][ty * 2 + 1];
            float2 b0 = Pc[mm][tx], b1 = Pc[mm][16 + tx];
            float2 b2 = Pc[mm][32 + tx], b3 = Pc[mm][48 + tx];
            // q += a * conj(b)
            #define QMAC(qq, aa, bb) \
                qq.x = fmaf(aa.x, bb.x, qq.x); qq.x = fmaf(aa.y, bb.y, qq.x); \
                qq.y = fmaf(aa.y, bb.x, qq.y); qq.y = fmaf(-aa.x, bb.y, qq.y);
            QMAC(q[0][0], a0, b0) QMAC(q[0][1], a0, b1) QMAC(q[0][2], a0, b2) QMAC(q[0][3], a0, b3)
            QMAC(q[1][0], a1, b0) QMAC(q[1][1], a1, b1) QMAC(q[1][2], a1, b2) QMAC(q[1][3], a1, b3)
            #undef QMAC
        }
        __syncthreads();
    }
    #pragma unroll
    for (int i = 0; i < 2; ++i) {
        int n = n0 + ty * 2 + i;
        #pragma unroll
        for (int j = 0; j < 4; ++j) {
            int c = c0 + j * 16 + tx;
            if (n < Nn && c < Nn && c >= n) {
                // M = I - step*Q : identity folds onto the real diagonal
                float MR = fmaf(nstep, q[i][j].x, (n == c) ? 1.0f : 0.0f);
                float MI = nstep * q[i][j].y;
                unsigned short hR = f16bits(MR);
                unsigned short hI = f16bits(MI);
                unsigned short nhI = hI ^ 0x8000u;
                int jr = ((c >> 5) * 64) + (c & 31);
                Bu[swzB(jr, n)]      = (unsigned)hR | ((unsigned)nhI << 16);  // Re row
                Bu[swzB(jr + 32, n)] = (unsigned)hI | ((unsigned)hR << 16);   // Im row
                if (c > n) {
                    // mirror entry (row c, col n): M[c][n] = conj(M[n][c]) = (MR, -MI)
                    int jm = ((n >> 5) * 64) + (n & 31);
                    Bu[swzB(jm, c)]      = (unsigned)hR | ((unsigned)hI << 16);   // Re row
                    Bu[swzB(jm + 32, c)] = (unsigned)nhI | ((unsigned)hR << 16);  // Im row
                }
            }
        }
    }
}

// ---------------- rpack: r -> f16 pairs in A2 layout (K=640) ----------------
__global__ void rpack_kernel(const float* __restrict__ rr, const float* __restrict__ ri,
                             unsigned int* __restrict__ rp16) {
    int b = blockIdx.x * 256 + threadIdx.x;
    int m = blockIdx.y;
    rp16[swzA2(b, m)] = (unsigned)f16bits(rr[(size_t)b * Mm + m]) |
                        ((unsigned)f16bits(ri[(size_t)b * Mm + m]) << 16);
}

// ---------------- ppack2: B2 = -step*conj(phi) pack, K=640 layout ----------------
__global__ void ppack2_kernel(const float* __restrict__ pr, const float* __restrict__ pi,
                              unsigned int* __restrict__ B2u, const float* __restrict__ sc) {
    int n = blockIdx.x * 256 + threadIdx.x;
    int m = blockIdx.y;
    if (n >= Nn) return;
    float s = sc[0];
    float xr = pr[(size_t)m * Nn + n], xi = pi[(size_t)m * Nn + n];
    unsigned short x = f16bits(-s * xr), y = f16bits(-s * xi);
    int jr2 = ((n >> 5) * 64) + (n & 31);
    B2u[swzB2(jr2, m)]      = (unsigned)x | ((unsigned)y << 16);
    B2u[swzB2(jr2 + 32, m)] = (unsigned)(y ^ 0x8000u) | ((unsigned)x << 16);
}

// ---------------- rphi_mfma: rph16 = -(rpack · B2) = f16(step * r * conj(phi)) ----------
// single-buffered, implicit TLP overlap (2 blocks/CU)
__global__ __launch_bounds__(256, 2) void rphi_mfma_kernel(
    const _Float16* __restrict__ rp16, const _Float16* __restrict__ B2,
    unsigned int* __restrict__ rph16) {
    __shared__ _Float16 As[8192];
    __shared__ _Float16 Bs[8192];
    int tid = threadIdx.x;
    int lane = tid & 63, wv = tid >> 6;
    int wm = wv & 1, wn = wv >> 1;
    int bblk = blockIdx.x, nblk = blockIdx.y;
    int l31 = lane & 31, lh = lane >> 5;

    f32x16 acc[2][2] = {};

    for (int kt = 0; kt < 10; ++kt) {
        #pragma unroll
        for (int c = 0; c < 4; ++c) {
            int u = c * 256 + tid;
            const char* ga = (const char*)rp16 + (((size_t)(bblk * 10 + kt)) * 1024 + u) * 16;
            load_lds16(ga, &As[(size_t)(c * 256 + wv * 64) * 8]);
            const char* gb = (const char*)B2 + (((size_t)(nblk * 10 + kt)) * 1024 + u) * 16;
            load_lds16(gb, &Bs[(size_t)(c * 256 + wv * 64) * 8]);
        }
        __syncthreads();
        #pragma unroll
        for (int s = 0; s < 4; ++s) {
            int kq = s * 2 + lh;
            f16x8 af[2], bfr[2];
            #pragma unroll
            for (int mt = 0; mt < 2; ++mt)
                af[mt] = *reinterpret_cast<const f16x8*>(
                    &As[(size_t)(kq * 128 + wm * 64 + mt * 32 + l31) * 8]);
            #pragma unroll
            for (int nt = 0; nt < 2; ++nt)
                bfr[nt] = *reinterpret_cast<const f16x8*>(
                    &Bs[(size_t)(kq * 128 + wn * 64 + nt * 32 + l31) * 8]);
            #pragma unroll
            for (int mt = 0; mt < 2; ++mt)
                #pragma unroll
                for (int nt = 0; nt < 2; ++nt)
                    acc[mt][nt] = __builtin_amdgcn_mfma_f32_32x32x16_f16(af[mt], bfr[nt], acc[mt][nt], 0, 0, 0);
        }
        __syncthreads();
    }

    int b0 = bblk * 128;
    int c = nblk * 64 + wn * 32 + l31;
    #pragma unroll
    for (int mt = 0; mt < 2; ++mt) {
        #pragma unroll
        for (int reg = 0; reg < 16; ++reg) {
            int row = b0 + wm * 64 + mt * 32 + ((reg & 3) + 8 * (reg >> 2) + 4 * lh);
            rph16[(size_t)row * NCP + c] =
                (unsigned)f16bits(-acc[mt][0][reg]) | ((unsigned)f16bits(-acc[mt][1][reg]) << 16);
        }
    }
}

// ---------------- fused ISTA loop (cooperative): all 50 iterations in one kernel -------
// Body = r8's proven ista9 (512 thr, 8 waves 2m x 4n, tile 128x128, A+B LDS static dbuf,
// counted vmcnt(6), raw barriers, 31 k-tiles, XCD-tiled remap). Between iterations:
// __threadfence() (device-scope release: L2 writeback) + grid.sync() + __threadfence()
// (acquire: invalidate stale L2 lines from other XCDs). Grid 256 = 1 block/CU at 96 KB
// LDS -> all blocks co-resident as cooperative launch requires. Removes 49 kernel
// launch+drain boundaries.
__global__ __launch_bounds__(512) void ista_coop_kernel(
    _Float16* __restrict__ wf0, _Float16* __restrict__ wf1,
    const _Float16* __restrict__ Bq,
    const unsigned int* __restrict__ rph16,
    const float* __restrict__ sc, float* __restrict__ out) {
    cg::grid_group grid = cg::this_grid();
    __shared__ _Float16 As0[8192], As1[8192];           // A k-tile dbuf (16 KB each)
    __shared__ _Float16 Bs0[2][8192], Bs1[2][8192];     // B k-tile dbuf (2 x 64-col slabs)
    int tid = threadIdx.x;
    int lane = tid & 63, wv = tid >> 6;          // wv 0..7
    int wm = wv >> 2, wn = wv & 3;               // wm: row half; wn: 32-col group 0..3
    int id = blockIdx.x;
    int x = id & 7;                              // XCD (round-robin dispatch)
    int n = id >> 3;                             // 0..31 within XCD
    int bblk = (x & 3) * 8 + (n & 7);            // 0..31 (128-row group) ; 8 per XCD
    int nb2  = (x >> 2) * 4 + (n >> 3);          // 0..7  (128-col group) ; 4 per XCD
    int l31 = lane & 31, lh = lane >> 5;
    int slab = wn >> 1, chg = wn & 1;            // B slab + 32-col group within slab

    const char* gB0 = (const char*)Bq + (size_t)(nb2 * 2 + 0) * 32 * 1024 * 16;
    const char* gB1 = (const char*)Bq + (size_t)(nb2 * 2 + 1) * 32 * 1024 * 16;
    float thr = sc[1];
    int b0 = bblk * 128;
    int c = nb2 * 128 + wn * 32 + l31;           // complex col for this lane

    #define STAGE9(kt, Ad, Bd)                                                        \
        {                                                                             \
            _Float16* Ap = (Ad);                                                      \
            _Float16* Bp0 = &(Bd)[0][0];                                              \
            _Float16* Bp1 = &(Bd)[1][0];                                              \
            _Pragma("unroll")                                                         \
            for (int cc = 0; cc < 2; ++cc) {                                          \
                int u = cc * 512 + tid;                                               \
                size_t ldst = (size_t)(cc * 512 + wv * 64) * 8;                       \
                load_lds16(gA + ((size_t)(kt) * 1024 + u) * 16, &Ap[ldst]);           \
                load_lds16(gB0 + ((size_t)(kt) * 1024 + u) * 16, &Bp0[ldst]);         \
                load_lds16(gB1 + ((size_t)(kt) * 1024 + u) * 16, &Bp1[ldst]);         \
            }                                                                         \
        }

    #define COMPUTE9(Asrc, Bsrc)                                                      \
        {                                                                             \
            _Pragma("unroll")                                                         \
            for (int s = 0; s < 4; ++s) {                                             \
                int kq = s * 2 + lh;                                                  \
                f16x8 af[2], bf[2];                                                   \
                _Pragma("unroll")                                                     \
                for (int mt = 0; mt < 2; ++mt)                                        \
                    af[mt] = *reinterpret_cast<const f16x8*>(                         \
                        &(Asrc)[(size_t)(kq * 128 + wm * 64 + mt * 32 + l31) * 8]);   \
                _Pragma("unroll")                                                     \
                for (int nt = 0; nt < 2; ++nt)                                        \
                    bf[nt] = *reinterpret_cast<const f16x8*>(                         \
                        &(Bsrc)[slab][(size_t)(kq * 128 + chg * 64 + nt * 32 + l31) * 8]); \
                _Pragma("unroll")                                                     \
                for (int mt = 0; mt < 2; ++mt)                                        \
                    _Pragma("unroll")                                                 \
                    for (int nt = 0; nt < 2; ++nt)                                    \
                        acc[mt][nt] = __builtin_amdgcn_mfma_f32_32x32x16_f16(         \
                            af[mt], bf[nt], acc[mt][nt], 0, 0, 0);                    \
            }                                                                         \
        }

    for (int it = 0; it < ITERS; ++it) {
        const _Float16* wfi = (it & 1) ? wf1 : wf0;
        unsigned int* wfo = (unsigned int*)((it & 1) ? wf0 : wf1);
        const char* gA = (const char*)wfi + (size_t)bblk * 32 * 1024 * 16;

        f32x16 acc[2][2] = {};                   // [mt][nt: 0=Re,1=Im]

        STAGE9(0, As0, Bs0);
        for (int kt = 0; kt < 30; kt += 2) {
            STAGE9(kt + 1, As1, Bs1);
            asm volatile("s_waitcnt vmcnt(6)" ::: "memory");   // tile kt landed; kt+1 in flight
            __builtin_amdgcn_s_barrier();
            COMPUTE9(As0, Bs0);
            __builtin_amdgcn_s_barrier();
            STAGE9(kt + 2, As0, Bs0);                          // max kt+2 = 30 (in bounds)
            asm volatile("s_waitcnt vmcnt(6)" ::: "memory");   // tile kt+1 landed
            __builtin_amdgcn_s_barrier();
            COMPUTE9(As1, Bs1);
            __builtin_amdgcn_s_barrier();
        }
        asm volatile("s_waitcnt vmcnt(0)" ::: "memory");
        __builtin_amdgcn_s_barrier();
        COMPUTE9(As0, Bs0);
        // tile 31 skipped: structurally zero (w and Bq cols 992..1023 are padding zeros)

        int last = (it == ITERS - 1);
        #pragma unroll
        for (int mt = 0; mt < 2; ++mt) {
            #pragma unroll
            for (int reg = 0; reg < 16; ++reg) {
                int row = b0 + wm * 64 + mt * 32 + ((reg & 3) + 8 * (reg >> 2) + 4 * lh);
                unsigned int ru = rph16[(size_t)row * NCP + c];
                float zr = acc[mt][0][reg] + f16lo(ru);
                float zi = acc[mt][1][reg] + f16hi(ru);
                float mag = sqrtf(zr * zr + zi * zi);
                float nm = mag - thr;
                float f = (nm > 0.f) ? (nm / mag) : 0.f;
                wfo[swzA(row, c)] = (unsigned)f16bits(zr * f) | ((unsigned)f16bits(zi * f) << 16);
                if (last && c < Nn) out[(size_t)row * Nn + c] = fmaxf(nm, 0.f);
            }
        }

        __threadfence();      // release: write back this XCD's L2 before the barrier
        grid.sync();
        __threadfence();      // acquire: invalidate stale lines cached from prior reads
    }
    #undef STAGE9
    #undef COMPUTE9
}

extern "C" void kernel_launch(void* const* d_in, const int* in_sizes, int n_in,
                              void* d_out, int out_size, void* d_ws, size_t ws_size,
                              hipStream_t stream) {
    const float* rr = (const float*)d_in[0];
    const float* ri = (const float*)d_in[1];
    const float* pr = (const float*)d_in[2];
    const float* pi = (const float*)d_in[3];
    float* out = (float*)d_out;

    char* ws = (char*)d_ws;
    size_t off = 0;
    _Float16* wf0 = (_Float16*)(ws + off); off += (size_t)Bb * KA * sizeof(_Float16);   // 16 MB
    _Float16* wf1 = (_Float16*)(ws + off); off += (size_t)Bb * KA * sizeof(_Float16);   // 16 MB
    _Float16* Bq  = (_Float16*)(ws + off); off += (size_t)2048 * 2048 * sizeof(_Float16); // 8 MB
    unsigned int* rph16 = (unsigned int*)(ws + off); off += (size_t)Bb * NCP * 4;       // 16 MB
    _Float16* rp16 = (_Float16*)(ws + off); off += (size_t)Bb * 640 * sizeof(_Float16);   // 5.2 MB
    _Float16* B2  = (_Float16*)(ws + off); off += (size_t)2048 * 640 * sizeof(_Float16);  // 2.6 MB
    float2* G = (float2*)(ws + off);     off += (size_t)Mm * Mm * sizeof(float2);
    float2* H1 = (float2*)(ws + off);    off += (size_t)Mm * Mm * sizeof(float2);
    float2* H2 = (float2*)(ws + off);    off += (size_t)Mm * Mm * sizeof(float2);
    float2* vvec = (float2*)(ws + off);  off += (size_t)Mm * sizeof(float2);
    float* slots = (float*)(ws + off);   off += 64 * sizeof(float);
    float* sc = slots + 32;

    (void)hipMemsetAsync(wf0, 0, (size_t)Bb * KA * sizeof(_Float16), stream);
    (void)hipMemsetAsync(Bq, 0, (size_t)2048 * 2048 * sizeof(_Float16), stream);
    (void)hipMemsetAsync(rp16, 0, (size_t)Bb * 640 * sizeof(_Float16), stream);
    (void)hipMemsetAsync(B2, 0, (size_t)2048 * 640 * sizeof(_Float16), stream);
    (void)hipMemsetAsync(slots, 0, 64 * sizeof(float), stream);
    (void)hipMemsetAsync(G, 0, (size_t)Mm * Mm * sizeof(float2), stream);

    // spectral norm chain on G (306x306): G -> normalize+square x KSQ -> Rayleigh
    gram_kernel<<<dim3(10, 10, 4), dim3(16, 16), 0, stream>>>(pr, pi, G);
    float2* bufs[2] = { H1, H2 };
    const float2* src = G;
    for (int s = 0; s < KSQ; ++s) {
        float2* dst = bufs[s & 1];
        frobz_kernel<<<128, 256, 0, stream>>>(src, slots + s, dst, Mm * Mm);
        sqmm_kernel<<<dim3(10, 10, 4), dim3(16, 16), 0, stream>>>(src, dst, slots + s);
        src = dst;
    }
    ray1_kernel<<<Mm, 256, 0, stream>>>(src, vvec);
    ray2_kernel<<<Mm, 256, 0, stream>>>(G, vvec, slots);
    ray3_kernel<<<1, 1, 0, stream>>>(slots, sc);

    // precompute: packed operator (I - step*Q f16), r pack, -step*conj(phi) pack, rphi MFMA
    qpack_kernel<<<dim3(31, 16), 256, 0, stream>>>(pr, pi, (unsigned int*)Bq, sc);
    rpack_kernel<<<dim3(16, Mm), 256, 0, stream>>>(rr, ri, (unsigned int*)rp16);
    ppack2_kernel<<<dim3(4, Mm), 256, 0, stream>>>(pr, pi, (unsigned int*)B2, sc);
    rphi_mfma_kernel<<<dim3(32, 16), 256, 0, stream>>>(rp16, B2, rph16);

    // fused ISTA loop: one cooperative launch, grid.sync between iterations
    {
        _Float16* a0 = wf0; _Float16* a1 = wf1;
        const _Float16* bq = Bq;
        const unsigned int* rp = rph16;
        const float* scp = sc;
        float* op = out;
        void* args[] = { &a0, &a1, &bq, &rp, &scp, &op };
        (void)hipLaunchCooperativeKernel((const void*)ista_coop_kernel,
                                         dim3(256), dim3(512), args, 0, stream);
    }
}

// Round 12
// 2789.606 us; speedup vs baseline: 3.0147x; 3.0147x over previous
//
#include <hip/hip_runtime.h>
#include <math.h>

#define Bb 4096
#define Mm 306
#define Nn 984      // complex cols
#define NCP 1024    // padded complex cols
#define KA 2048     // w real k-cols (padded)
#define ITERS 50
#define KSQ 9       // squaring stages: G^(2^9) then Rayleigh

typedef _Float16 f16x8 __attribute__((ext_vector_type(8)));
typedef float f32x16 __attribute__((ext_vector_type(16)));

__device__ __forceinline__ void cmac(float2& c, const float2 a, const float2 b) {
    c.x = fmaf(a.x, b.x, c.x);
    c.x = fmaf(-a.y, b.y, c.x);
    c.y = fmaf(a.x, b.y, c.y);
    c.y = fmaf(a.y, b.x, c.y);
}

__device__ __forceinline__ unsigned short f16bits(float v) {
    union { _Float16 h; unsigned short u; } cv;
    cv.h = (_Float16)v;
    return cv.u;
}
__device__ __forceinline__ float f16lo(unsigned int u) {
    union { unsigned short s; _Float16 h; } cv; cv.s = (unsigned short)(u & 0xffffu);
    return (float)cv.h;
}
__device__ __forceinline__ float f16hi(unsigned int u) {
    union { unsigned short s; _Float16 h; } cv; cv.s = (unsigned short)(u >> 16);
    return (float)cv.h;
}

__device__ __forceinline__ void load_lds16(const void* g, void* l) {
    __builtin_amdgcn_global_load_lds((const __attribute__((address_space(1))) void*)g,
                                     (__attribute__((address_space(3))) void*)l, 16, 0, 0);
}

// ---- swizzled uint (4B) index, w/A operand (K=2048: 32 ktiles), (row b, complex col c) --
__device__ __forceinline__ size_t swzA(int b, int c) {
    return ((size_t)(((b >> 7) * 32 + (c >> 5)) * 1024 + ((c >> 2) & 7) * 128 + (b & 127))) * 4 + (c & 3);
}
// ---- B operand (Q op, K=2048: 32 ktiles), (row jr, uint col q) ----
__device__ __forceinline__ size_t swzB(int jr, int q) {
    return ((size_t)(((jr >> 7) * 32 + (q >> 5)) * 1024 + ((q >> 2) & 7) * 128 + (jr & 127))) * 4 + (q & 3);
}
// ---- A2 operand (r pack, K=640: 10 ktiles), (row b, complex col c<320) ----
__device__ __forceinline__ size_t swzA2(int b, int c) {
    return ((size_t)(((b >> 7) * 10 + (c >> 5)) * 1024 + ((c >> 2) & 7) * 128 + (b & 127))) * 4 + (c & 3);
}
// ---- B2 operand (-step*conj(phi) pack, K=640: 10 ktiles), (row jr, uint col q<320) ----
__device__ __forceinline__ size_t swzB2(int jr, int q) {
    return ((size_t)(((jr >> 7) * 10 + (q >> 5)) * 1024 + ((q >> 2) & 7) * 128 + (jr & 127))) * 4 + (q & 3);
}

// ---------------- G = phi * phi^H  (306x306 complex), tiled + split-K ----------------
__global__ void gram_kernel(const float* __restrict__ pr, const float* __restrict__ pi,
                            float2* __restrict__ G) {
    __shared__ float2 As[32][33];
    __shared__ float2 Bs[32][33];
    int tx = threadIdx.x, ty = threadIdx.y;
    int t = ty * 16 + tx;
    int i0 = blockIdx.y * 32, j0 = blockIdx.x * 32;
    int zs = blockIdx.z * 246;
    int ze = zs + 246 < Nn ? zs + 246 : Nn;
    float2 acc[2][2] = {};
    for (int k0 = zs; k0 < ze; k0 += 32) {
        #pragma unroll
        for (int rep = 0; rep < 4; ++rep) {
            int idx = t + rep * 256;
            int rr = idx >> 5, cc = idx & 31;
            int gk = k0 + cc;
            int gi = i0 + rr, gj = j0 + rr;
            float2 a = make_float2(0.f, 0.f), b = make_float2(0.f, 0.f);
            if (gk < ze) {
                if (gi < Mm) a = make_float2(pr[(size_t)gi * Nn + gk], pi[(size_t)gi * Nn + gk]);
                if (gj < Mm) b = make_float2(pr[(size_t)gj * Nn + gk], pi[(size_t)gj * Nn + gk]);
            }
            As[rr][cc] = a; Bs[rr][cc] = b;
        }
        __syncthreads();
        #pragma unroll 8
        for (int kk = 0; kk < 32; ++kk) {
            float2 a0 = As[ty * 2][kk], a1 = As[ty * 2 + 1][kk];
            float2 b0 = Bs[tx * 2][kk], b1 = Bs[tx * 2 + 1][kk];
            #define GMAC(qq, aa, bb) \
                qq.x = fmaf(aa.x, bb.x, qq.x); qq.x = fmaf(aa.y, bb.y, qq.x); \
                qq.y = fmaf(aa.y, bb.x, qq.y); qq.y = fmaf(-aa.x, bb.y, qq.y);
            GMAC(acc[0][0], a0, b0) GMAC(acc[0][1], a0, b1)
            GMAC(acc[1][0], a1, b0) GMAC(acc[1][1], a1, b1)
            #undef GMAC
        }
        __syncthreads();
    }
    #pragma unroll
    for (int i = 0; i < 2; ++i) {
        int gi = i0 + ty * 2 + i;
        #pragma unroll
        for (int j = 0; j < 2; ++j) {
            int gj = j0 + tx * 2 + j;
            if (gi < Mm && gj < Mm) {
                atomicAdd(&G[gi * Mm + gj].x, acc[i][j].x);
                atomicAdd(&G[gi * Mm + gj].y, acc[i][j].y);
            }
        }
    }
}

// ---------------- frobz: Frobenius^2 of src + zero dst (fused with next-stage memset) ----
__global__ void frobz_kernel(const float2* __restrict__ H, float* __restrict__ slot,
                             float2* __restrict__ dst, int n) {
    int idx = blockIdx.x * blockDim.x + threadIdx.x;
    int stride = gridDim.x * blockDim.x;
    float s = 0.f;
    for (int i = idx; i < n; i += stride) {
        float2 v = H[i];
        s = fmaf(v.x, v.x, s);
        s = fmaf(v.y, v.y, s);
        dst[i] = make_float2(0.f, 0.f);
    }
    #pragma unroll
    for (int o = 32; o > 0; o >>= 1) s += __shfl_down(s, o, 64);
    __shared__ float wsum[4];
    int lane = threadIdx.x & 63, wv = threadIdx.x >> 6;
    if (lane == 0) wsum[wv] = s;
    __syncthreads();
    if (threadIdx.x == 0) atomicAdd(slot, wsum[0] + wsum[1] + wsum[2] + wsum[3]);
}

// ---------------- C += (A/||A||_F)^2 partial (split-K, C pre-zeroed) ----------------
__global__ void sqmm_kernel(const float2* __restrict__ A, float2* __restrict__ C,
                            const float* __restrict__ fslot) {
    __shared__ float2 As[32][33];
    __shared__ float2 Bs[32][33];
    float inv = 1.0f / fslot[0];
    int tx = threadIdx.x, ty = threadIdx.y;
    int t = ty * 16 + tx;
    int r0 = blockIdx.y * 32, c0 = blockIdx.x * 32;
    int zs = blockIdx.z * 80;
    int ze = zs + 80 < Mm ? zs + 80 : Mm;
    float2 acc[2][2] = {};
    for (int k0 = zs; k0 < ze; k0 += 32) {
        #pragma unroll
        for (int i = 0; i < 4; ++i) {
            int idx = t + i * 256;
            int rr = idx >> 5, cc = idx & 31;
            int gr = r0 + rr, gk = k0 + cc;
            As[rr][cc] = (gr < Mm && gk < ze) ? A[gr * Mm + gk] : make_float2(0.f, 0.f);
            int gk2 = k0 + rr, gc = c0 + cc;
            Bs[rr][cc] = (gk2 < ze && gc < Mm) ? A[gk2 * Mm + gc] : make_float2(0.f, 0.f);
        }
        __syncthreads();
        #pragma unroll 8
        for (int kk = 0; kk < 32; ++kk) {
            float2 a0 = As[ty * 2][kk], a1 = As[ty * 2 + 1][kk];
            float2 b0 = Bs[kk][tx * 2], b1 = Bs[kk][tx * 2 + 1];
            cmac(acc[0][0], a0, b0); cmac(acc[0][1], a0, b1);
            cmac(acc[1][0], a1, b0); cmac(acc[1][1], a1, b1);
        }
        __syncthreads();
    }
    #pragma unroll
    for (int i = 0; i < 2; ++i) {
        int gr = r0 + ty * 2 + i;
        #pragma unroll
        for (int j = 0; j < 2; ++j) {
            int gc = c0 + tx * 2 + j;
            if (gr < Mm && gc < Mm) {
                atomicAdd(&C[gr * Mm + gc].x, acc[i][j].x * inv);
                atomicAdd(&C[gr * Mm + gc].y, acc[i][j].y * inv);
            }
        }
    }
}

// ---------------- Rayleigh, parallelized: ray1 v=H*ones; ray2 num/den; ray3 sc ----------
__global__ void ray1_kernel(const float2* __restrict__ H, float2* __restrict__ v) {
    int t = blockIdx.x;          // row 0..Mm-1
    int k = threadIdx.x;         // 256 threads
    float sx = 0.f, sy = 0.f;
    for (int j = k; j < Mm; j += 256) {
        float2 h = H[(size_t)t * Mm + j];
        sx += h.x; sy += h.y;
    }
    #pragma unroll
    for (int o = 32; o > 0; o >>= 1) { sx += __shfl_down(sx, o, 64); sy += __shfl_down(sy, o, 64); }
    __shared__ float wx[4], wy[4];
    int lane = k & 63, wv = k >> 6;
    if (lane == 0) { wx[wv] = sx; wy[wv] = sy; }
    __syncthreads();
    if (k == 0) v[t] = make_float2(wx[0] + wx[1] + wx[2] + wx[3],
                                   wy[0] + wy[1] + wy[2] + wy[3]);
}

__global__ void ray2_kernel(const float2* __restrict__ G, const float2* __restrict__ v,
                            float* __restrict__ slots) {
    int t = blockIdx.x;
    int k0 = threadIdx.x;
    float ux = 0.f, uy = 0.f;
    for (int k = k0; k < Mm; k += 256) {
        float2 g = G[(size_t)k * Mm + t];
        float2 vk = v[k];
        ux = fmaf(g.x, vk.x, ux); ux = fmaf(g.y, vk.y, ux);
        uy = fmaf(g.x, vk.y, uy); uy = fmaf(-g.y, vk.x, uy);
    }
    #pragma unroll
    for (int o = 32; o > 0; o >>= 1) { ux += __shfl_down(ux, o, 64); uy += __shfl_down(uy, o, 64); }
    __shared__ float wx[4], wy[4];
    int lane = k0 & 63, wv = k0 >> 6;
    if (lane == 0) { wx[wv] = ux; wy[wv] = uy; }
    __syncthreads();
    if (k0 == 0) {
        float sux = wx[0] + wx[1] + wx[2] + wx[3];
        float suy = wy[0] + wy[1] + wy[2] + wy[3];
        float2 vt = v[t];
        atomicAdd(&slots[16], vt.x * sux + vt.y * suy);   // num partial
        atomicAdd(&slots[17], vt.x * vt.x + vt.y * vt.y); // den partial
    }
}

__global__ void ray3_kernel(const float* __restrict__ slots, float* __restrict__ sc) {
    float step = slots[17] / slots[16];   // 1/lambda = den/num
    sc[0] = step;
    sc[1] = 0.1f * step;
}

// ---------------- qpack: M = I - step*Q, Hermitian-exploiting -----------------------
// Q[n][c] = sum_m phi[m][n]*conj(phi[m][c]); Q[c][n] = conj(Q[n][c]) exactly.
// Blocks entirely below the diagonal (all c < n) are skipped (~45% of grid); kept
// blocks write (n,c) for c >= n and mirror-write conj at (c,n) for c > n. Every
// entry written exactly once. 2x4 micro-tile, conflict-free Pc mapping (j*16+tx).
__global__ void qpack_kernel(const float* __restrict__ pr, const float* __restrict__ pi,
                             unsigned int* __restrict__ Bu, const float* __restrict__ sc) {
    __shared__ float2 Pn[16][33];
    __shared__ float2 Pc[16][65];
    int n0 = blockIdx.x * 32, c0 = blockIdx.y * 64;
    if (c0 + 64 <= n0) return;   // whole block has c < n: covered by mirror writes
    float nstep = -sc[0];
    int t = threadIdx.x;
    int tx = t & 15, ty = t >> 4;
    float2 q[2][4] = {};
    for (int m0 = 0; m0 < Mm; m0 += 16) {
        #pragma unroll
        for (int rep = 0; rep < 6; ++rep) {
            int idx = t + rep * 256;
            if (idx < 512) {
                int mm = idx >> 5, col = idx & 31;
                int gm = m0 + mm;
                float2 a = make_float2(0.f, 0.f);
                if (gm < Mm && n0 + col < Nn)
                    a = make_float2(pr[(size_t)gm * Nn + n0 + col], pi[(size_t)gm * Nn + n0 + col]);
                Pn[mm][col] = a;
            } else {
                int idx2 = idx - 512;
                int mm = idx2 >> 6, col = idx2 & 63;
                int gm = m0 + mm;
                float2 b = make_float2(0.f, 0.f);
                if (gm < Mm && c0 + col < Nn)
                    b = make_float2(pr[(size_t)gm * Nn + c0 + col], pi[(size_t)gm * Nn + c0 + col]);
                Pc[mm][col] = b;
            }
        }
        __syncthreads();
        #pragma unroll
        for (int mm = 0; mm < 16; ++mm) {
            float2 a0 = Pn[mm][ty * 2], a1 = Pn[mm][ty * 2 + 1];
            float2 b0 = Pc[mm][tx], b1 = Pc[mm][16 + tx];
            float2 b2 = Pc[mm][32 + tx], b3 = Pc[mm][48 + tx];
            // q += a * conj(b)
            #define QMAC(qq, aa, bb) \
                qq.x = fmaf(aa.x, bb.x, qq.x); qq.x = fmaf(aa.y, bb.y, qq.x); \
                qq.y = fmaf(aa.y, bb.x, qq.y); qq.y = fmaf(-aa.x, bb.y, qq.y);
            QMAC(q[0][0], a0, b0) QMAC(q[0][1], a0, b1) QMAC(q[0][2], a0, b2) QMAC(q[0][3], a0, b3)
            QMAC(q[1][0], a1, b0) QMAC(q[1][1], a1, b1) QMAC(q[1][2], a1, b2) QMAC(q[1][3], a1, b3)
            #undef QMAC
        }
        __syncthreads();
    }
    #pragma unroll
    for (int i = 0; i < 2; ++i) {
        int n = n0 + ty * 2 + i;
        #pragma unroll
        for (int j = 0; j < 4; ++j) {
            int c = c0 + j * 16 + tx;
            if (n < Nn && c < Nn && c >= n) {
                // M = I - step*Q : identity folds onto the real diagonal
                float MR = fmaf(nstep, q[i][j].x, (n == c) ? 1.0f : 0.0f);
                float MI = nstep * q[i][j].y;
                unsigned short hR = f16bits(MR);
                unsigned short hI = f16bits(MI);
                unsigned short nhI = hI ^ 0x8000u;
                int jr = ((c >> 5) * 64) + (c & 31);
                Bu[swzB(jr, n)]      = (unsigned)hR | ((unsigned)nhI << 16);  // Re row
                Bu[swzB(jr + 32, n)] = (unsigned)hI | ((unsigned)hR << 16);   // Im row
                if (c > n) {
                    // mirror entry (row c, col n): M[c][n] = conj(M[n][c]) = (MR, -MI)
                    int jm = ((n >> 5) * 64) + (n & 31);
                    Bu[swzB(jm, c)]      = (unsigned)hR | ((unsigned)hI << 16);   // Re row
                    Bu[swzB(jm + 32, c)] = (unsigned)nhI | ((unsigned)hR << 16);  // Im row
                }
            }
        }
    }
}

// ---------------- rpack: r -> f16 pairs in A2 layout (K=640) ----------------
__global__ void rpack_kernel(const float* __restrict__ rr, const float* __restrict__ ri,
                             unsigned int* __restrict__ rp16) {
    int b = blockIdx.x * 256 + threadIdx.x;
    int m = blockIdx.y;
    rp16[swzA2(b, m)] = (unsigned)f16bits(rr[(size_t)b * Mm + m]) |
                        ((unsigned)f16bits(ri[(size_t)b * Mm + m]) << 16);
}

// ---------------- ppack2: B2 = -step*conj(phi) pack, K=640 layout ----------------
__global__ void ppack2_kernel(const float* __restrict__ pr, const float* __restrict__ pi,
                              unsigned int* __restrict__ B2u, const float* __restrict__ sc) {
    int n = blockIdx.x * 256 + threadIdx.x;
    int m = blockIdx.y;
    if (n >= Nn) return;
    float s = sc[0];
    float xr = pr[(size_t)m * Nn + n], xi = pi[(size_t)m * Nn + n];
    unsigned short x = f16bits(-s * xr), y = f16bits(-s * xi);
    int jr2 = ((n >> 5) * 64) + (n & 31);
    B2u[swzB2(jr2, m)]      = (unsigned)x | ((unsigned)y << 16);
    B2u[swzB2(jr2 + 32, m)] = (unsigned)(y ^ 0x8000u) | ((unsigned)x << 16);
}

// ---------------- rphi_mfma: rph16 = -(rpack · B2) = f16(step * r * conj(phi)) ----------
// single-buffered, implicit TLP overlap (2 blocks/CU)
__global__ __launch_bounds__(256, 2) void rphi_mfma_kernel(
    const _Float16* __restrict__ rp16, const _Float16* __restrict__ B2,
    unsigned int* __restrict__ rph16) {
    __shared__ _Float16 As[8192];
    __shared__ _Float16 Bs[8192];
    int tid = threadIdx.x;
    int lane = tid & 63, wv = tid >> 6;
    int wm = wv & 1, wn = wv >> 1;
    int bblk = blockIdx.x, nblk = blockIdx.y;
    int l31 = lane & 31, lh = lane >> 5;

    f32x16 acc[2][2] = {};

    for (int kt = 0; kt < 10; ++kt) {
        #pragma unroll
        for (int c = 0; c < 4; ++c) {
            int u = c * 256 + tid;
            const char* ga = (const char*)rp16 + (((size_t)(bblk * 10 + kt)) * 1024 + u) * 16;
            load_lds16(ga, &As[(size_t)(c * 256 + wv * 64) * 8]);
            const char* gb = (const char*)B2 + (((size_t)(nblk * 10 + kt)) * 1024 + u) * 16;
            load_lds16(gb, &Bs[(size_t)(c * 256 + wv * 64) * 8]);
        }
        __syncthreads();
        #pragma unroll
        for (int s = 0; s < 4; ++s) {
            int kq = s * 2 + lh;
            f16x8 af[2], bfr[2];
            #pragma unroll
            for (int mt = 0; mt < 2; ++mt)
                af[mt] = *reinterpret_cast<const f16x8*>(
                    &As[(size_t)(kq * 128 + wm * 64 + mt * 32 + l31) * 8]);
            #pragma unroll
            for (int nt = 0; nt < 2; ++nt)
                bfr[nt] = *reinterpret_cast<const f16x8*>(
                    &Bs[(size_t)(kq * 128 + wn * 64 + nt * 32 + l31) * 8]);
            #pragma unroll
            for (int mt = 0; mt < 2; ++mt)
                #pragma unroll
                for (int nt = 0; nt < 2; ++nt)
                    acc[mt][nt] = __builtin_amdgcn_mfma_f32_32x32x16_f16(af[mt], bfr[nt], acc[mt][nt], 0, 0, 0);
        }
        __syncthreads();
    }

    int b0 = bblk * 128;
    int c = nblk * 64 + wn * 32 + l31;
    #pragma unroll
    for (int mt = 0; mt < 2; ++mt) {
        #pragma unroll
        for (int reg = 0; reg < 16; ++reg) {
            int row = b0 + wm * 64 + mt * 32 + ((reg & 3) + 8 * (reg >> 2) + 4 * lh);
            rph16[(size_t)row * NCP + c] =
                (unsigned)f16bits(-acc[mt][0][reg]) | ((unsigned)f16bits(-acc[mt][1][reg]) << 16);
        }
    }
}

// ---------------- main ISTA iteration (ista9): 512-thr block, tile 128x128 -------------
// 8 waves (2m x 4n), wave tile 64 rows x 32 complex cols. Static dbuf (96 KB LDS),
// counted vmcnt(6) + raw barriers. XCD-tiled block remap: each XCD owns an 8x4 tile of
// the 32x8 (rowgroup x colgroup) grid -> L2-local wfi AND Bq.
// K-loop runs 31 tiles (not 32): complex cols 992..1023 are structural zeros in both
// w and Bq (Nn=984 + padding), so k-tile 31 contributes exactly 0 and is skipped.
// Bq packs (I - step*Q): epilogue z = acc + rph.
__global__ __launch_bounds__(512) void ista9_kernel(
    const _Float16* __restrict__ wfi, const _Float16* __restrict__ Bq,
    unsigned int* __restrict__ wfo,
    const unsigned int* __restrict__ rph16,
    const float* __restrict__ sc, float* __restrict__ out, int last) {
    __shared__ _Float16 As0[8192], As1[8192];           // A k-tile dbuf (16 KB each)
    __shared__ _Float16 Bs0[2][8192], Bs1[2][8192];     // B k-tile dbuf (2 x 64-col slabs)
    int tid = threadIdx.x;
    int lane = tid & 63, wv = tid >> 6;          // wv 0..7
    int wm = wv >> 2, wn = wv & 3;               // wm: row half; wn: 32-col group 0..3
    int id = blockIdx.x;
    int x = id & 7;                              // XCD (round-robin dispatch)
    int n = id >> 3;                             // 0..31 within XCD
    int bblk = (x & 3) * 8 + (n & 7);            // 0..31 (128-row group) ; 8 per XCD
    int nb2  = (x >> 2) * 4 + (n >> 3);          // 0..7  (128-col group) ; 4 per XCD
    int l31 = lane & 31, lh = lane >> 5;
    int slab = wn >> 1, chg = wn & 1;            // B slab + 32-col group within slab

    f32x16 acc[2][2] = {};                       // [mt][nt: 0=Re,1=Im]

    const char* gA  = (const char*)wfi + (size_t)bblk * 32 * 1024 * 16;
    const char* gB0 = (const char*)Bq + (size_t)(nb2 * 2 + 0) * 32 * 1024 * 16;
    const char* gB1 = (const char*)Bq + (size_t)(nb2 * 2 + 1) * 32 * 1024 * 16;

    // stage one k-tile: A 1024 chunks + B 2x1024 chunks, 512 threads -> 6 loads/thread
    #define STAGE9(kt, Ad, Bd)                                                        \
        {                                                                             \
            _Float16* Ap = (Ad);                                                      \
            _Float16* Bp0 = &(Bd)[0][0];                                              \
            _Float16* Bp1 = &(Bd)[1][0];                                              \
            _Pragma("unroll")                                                         \
            for (int cc = 0; cc < 2; ++cc) {                                          \
                int u = cc * 512 + tid;                                               \
                size_t ldst = (size_t)(cc * 512 + wv * 64) * 8;                       \
                load_lds16(gA + ((size_t)(kt) * 1024 + u) * 16, &Ap[ldst]);           \
                load_lds16(gB0 + ((size_t)(kt) * 1024 + u) * 16, &Bp0[ldst]);         \
                load_lds16(gB1 + ((size_t)(kt) * 1024 + u) * 16, &Bp1[ldst]);         \
            }                                                                         \
        }

    #define COMPUTE9(Asrc, Bsrc)                                                      \
        {                                                                             \
            _Pragma("unroll")                                                         \
            for (int s = 0; s < 4; ++s) {                                             \
                int kq = s * 2 + lh;                                                  \
                f16x8 af[2], bf[2];                                                   \
                _Pragma("unroll")                                                     \
                for (int mt = 0; mt < 2; ++mt)                                        \
                    af[mt] = *reinterpret_cast<const f16x8*>(                         \
                        &(Asrc)[(size_t)(kq * 128 + wm * 64 + mt * 32 + l31) * 8]);   \
                _Pragma("unroll")                                                     \
                for (int nt = 0; nt < 2; ++nt)                                        \
                    bf[nt] = *reinterpret_cast<const f16x8*>(                         \
                        &(Bsrc)[slab][(size_t)(kq * 128 + chg * 64 + nt * 32 + l31) * 8]); \
                _Pragma("unroll")                                                     \
                for (int mt = 0; mt < 2; ++mt)                                        \
                    _Pragma("unroll")                                                 \
                    for (int nt = 0; nt < 2; ++nt)                                    \
                        acc[mt][nt] = __builtin_amdgcn_mfma_f32_32x32x16_f16(         \
                            af[mt], bf[nt], acc[mt][nt], 0, 0, 0);                    \
            }                                                                         \
        }

    STAGE9(0, As0, Bs0);
    for (int kt = 0; kt < 30; kt += 2) {
        STAGE9(kt + 1, As1, Bs1);
        asm volatile("s_waitcnt vmcnt(6)" ::: "memory");   // tile kt landed; kt+1's 6 in flight
        __builtin_amdgcn_s_barrier();
        COMPUTE9(As0, Bs0);
        __builtin_amdgcn_s_barrier();
        STAGE9(kt + 2, As0, Bs0);                          // max kt+2 = 30 (in bounds)
        asm volatile("s_waitcnt vmcnt(6)" ::: "memory");   // tile kt+1 landed
        __builtin_amdgcn_s_barrier();
        COMPUTE9(As1, Bs1);
        __builtin_amdgcn_s_barrier();
    }
    // tiles 0..29 computed; tile 30 staged into As0/Bs0 with 6 loads outstanding
    asm volatile("s_waitcnt vmcnt(0)" ::: "memory");
    __builtin_amdgcn_s_barrier();
    COMPUTE9(As0, Bs0);
    // tile 31 skipped: structurally zero (w and Bq cols 992..1023 are padding zeros)
    #undef STAGE9
    #undef COMPUTE9

    float thr = sc[1];
    int b0 = bblk * 128;
    int c = nb2 * 128 + wn * 32 + l31;   // complex col for this lane
    #pragma unroll
    for (int mt = 0; mt < 2; ++mt) {
        #pragma unroll
        for (int reg = 0; reg < 16; ++reg) {
            int row = b0 + wm * 64 + mt * 32 + ((reg & 3) + 8 * (reg >> 2) + 4 * lh);
            unsigned int ru = rph16[(size_t)row * NCP + c];
            float zr = acc[mt][0][reg] + f16lo(ru);
            float zi = acc[mt][1][reg] + f16hi(ru);
            float mag = sqrtf(zr * zr + zi * zi);
            float nm = mag - thr;
            float f = (nm > 0.f) ? (nm / mag) : 0.f;
            wfo[swzA(row, c)] = (unsigned)f16bits(zr * f) | ((unsigned)f16bits(zi * f) << 16);
            if (last && c < Nn) out[(size_t)row * Nn + c] = fmaxf(nm, 0.f);
        }
    }
}

extern "C" void kernel_launch(void* const* d_in, const int* in_sizes, int n_in,
                              void* d_out, int out_size, void* d_ws, size_t ws_size,
                              hipStream_t stream) {
    const float* rr = (const float*)d_in[0];
    const float* ri = (const float*)d_in[1];
    const float* pr = (const float*)d_in[2];
    const float* pi = (const float*)d_in[3];
    float* out = (float*)d_out;

    char* ws = (char*)d_ws;
    size_t off = 0;
    _Float16* wf0 = (_Float16*)(ws + off); off += (size_t)Bb * KA * sizeof(_Float16);   // 16 MB
    _Float16* wf1 = (_Float16*)(ws + off); off += (size_t)Bb * KA * sizeof(_Float16);   // 16 MB
    _Float16* Bq  = (_Float16*)(ws + off); off += (size_t)2048 * 2048 * sizeof(_Float16); // 8 MB
    unsigned int* rph16 = (unsigned int*)(ws + off); off += (size_t)Bb * NCP * 4;       // 16 MB
    _Float16* rp16 = (_Float16*)(ws + off); off += (size_t)Bb * 640 * sizeof(_Float16);   // 5.2 MB
    _Float16* B2  = (_Float16*)(ws + off); off += (size_t)2048 * 640 * sizeof(_Float16);  // 2.6 MB
    float2* G = (float2*)(ws + off);     off += (size_t)Mm * Mm * sizeof(float2);
    float2* H1 = (float2*)(ws + off);    off += (size_t)Mm * Mm * sizeof(float2);
    float2* H2 = (float2*)(ws + off);    off += (size_t)Mm * Mm * sizeof(float2);
    float2* vvec = (float2*)(ws + off);  off += (size_t)Mm * sizeof(float2);
    float* slots = (float*)(ws + off);   off += 64 * sizeof(float);
    float* sc = slots + 32;

    (void)hipMemsetAsync(wf0, 0, (size_t)Bb * KA * sizeof(_Float16), stream);
    (void)hipMemsetAsync(Bq, 0, (size_t)2048 * 2048 * sizeof(_Float16), stream);
    (void)hipMemsetAsync(rp16, 0, (size_t)Bb * 640 * sizeof(_Float16), stream);
    (void)hipMemsetAsync(B2, 0, (size_t)2048 * 640 * sizeof(_Float16), stream);
    (void)hipMemsetAsync(slots, 0, 64 * sizeof(float), stream);
    (void)hipMemsetAsync(G, 0, (size_t)Mm * Mm * sizeof(float2), stream);

    // spectral norm chain on G (306x306): G -> normalize+square x KSQ -> Rayleigh
    gram_kernel<<<dim3(10, 10, 4), dim3(16, 16), 0, stream>>>(pr, pi, G);
    float2* bufs[2] = { H1, H2 };
    const float2* src = G;
    for (int s = 0; s < KSQ; ++s) {
        float2* dst = bufs[s & 1];
        frobz_kernel<<<128, 256, 0, stream>>>(src, slots + s, dst, Mm * Mm);
        sqmm_kernel<<<dim3(10, 10, 4), dim3(16, 16), 0, stream>>>(src, dst, slots + s);
        src = dst;
    }
    ray1_kernel<<<Mm, 256, 0, stream>>>(src, vvec);
    ray2_kernel<<<Mm, 256, 0, stream>>>(G, vvec, slots);
    ray3_kernel<<<1, 1, 0, stream>>>(slots, sc);

    // precompute: packed operator (I - step*Q f16), r pack, -step*conj(phi) pack, rphi MFMA
    qpack_kernel<<<dim3(31, 16), 256, 0, stream>>>(pr, pi, (unsigned int*)Bq, sc);
    rpack_kernel<<<dim3(16, Mm), 256, 0, stream>>>(rr, ri, (unsigned int*)rp16);
    ppack2_kernel<<<dim3(4, Mm), 256, 0, stream>>>(pr, pi, (unsigned int*)B2, sc);
    rphi_mfma_kernel<<<dim3(32, 16), 256, 0, stream>>>(rp16, B2, rph16);

    // ISTA main loop: one fused MFMA GEMM per iteration, f16 state ping-pong
    _Float16* wbuf[2] = { wf0, wf1 };
    for (int it = 0; it < ITERS; ++it) {
        ista9_kernel<<<256, 512, 0, stream>>>(
            wbuf[it & 1], Bq, (unsigned int*)wbuf[(it + 1) & 1], rph16, sc, out,
            it == ITERS - 1 ? 1 : 0);
    }
}

// Round 13
// 2774.097 us; speedup vs baseline: 3.0316x; 1.0056x over previous
//
#include <hip/hip_runtime.h>
#include <math.h>

#define Bb 4096
#define Mm 306
#define Nn 984      // complex cols
#define NCP 1024    // padded complex cols
#define KA 2048     // w real k-cols (padded)
#define ITERS 50
#define KSQ 9       // squaring stages: G^(2^9) then Rayleigh

typedef _Float16 f16x8 __attribute__((ext_vector_type(8)));
typedef float f32x16 __attribute__((ext_vector_type(16)));

__device__ __forceinline__ void cmac(float2& c, const float2 a, const float2 b) {
    c.x = fmaf(a.x, b.x, c.x);
    c.x = fmaf(-a.y, b.y, c.x);
    c.y = fmaf(a.x, b.y, c.y);
    c.y = fmaf(a.y, b.x, c.y);
}

__device__ __forceinline__ unsigned short f16bits(float v) {
    union { _Float16 h; unsigned short u; } cv;
    cv.h = (_Float16)v;
    return cv.u;
}
__device__ __forceinline__ float f16lo(unsigned int u) {
    union { unsigned short s; _Float16 h; } cv; cv.s = (unsigned short)(u & 0xffffu);
    return (float)cv.h;
}
__device__ __forceinline__ float f16hi(unsigned int u) {
    union { unsigned short s; _Float16 h; } cv; cv.s = (unsigned short)(u >> 16);
    return (float)cv.h;
}

__device__ __forceinline__ void load_lds16(const void* g, void* l) {
    __builtin_amdgcn_global_load_lds((const __attribute__((address_space(1))) void*)g,
                                     (__attribute__((address_space(3))) void*)l, 16, 0, 0);
}

// ---- swizzled uint (4B) index, w/A operand (K=2048: 32 ktiles), (row b, complex col c) --
__device__ __forceinline__ size_t swzA(int b, int c) {
    return ((size_t)(((b >> 7) * 32 + (c >> 5)) * 1024 + ((c >> 2) & 7) * 128 + (b & 127))) * 4 + (c & 3);
}
// ---- B operand (Q op, K=2048: 32 ktiles), (row jr, uint col q) ----
__device__ __forceinline__ size_t swzB(int jr, int q) {
    return ((size_t)(((jr >> 7) * 32 + (q >> 5)) * 1024 + ((q >> 2) & 7) * 128 + (jr & 127))) * 4 + (q & 3);
}
// ---- A2 operand (r pack, K=640: 10 ktiles), (row b, complex col c<320) ----
__device__ __forceinline__ size_t swzA2(int b, int c) {
    return ((size_t)(((b >> 7) * 10 + (c >> 5)) * 1024 + ((c >> 2) & 7) * 128 + (b & 127))) * 4 + (c & 3);
}
// ---- B2 operand (-step*conj(phi) pack, K=640: 10 ktiles), (row jr, uint col q<320) ----
__device__ __forceinline__ size_t swzB2(int jr, int q) {
    return ((size_t)(((jr >> 7) * 10 + (q >> 5)) * 1024 + ((q >> 2) & 7) * 128 + (jr & 127))) * 4 + (q & 3);
}

// ---------------- G = phi * phi^H  (306x306 complex), tiled + split-K ----------------
__global__ void gram_kernel(const float* __restrict__ pr, const float* __restrict__ pi,
                            float2* __restrict__ G) {
    __shared__ float2 As[32][33];
    __shared__ float2 Bs[32][33];
    int tx = threadIdx.x, ty = threadIdx.y;
    int t = ty * 16 + tx;
    int i0 = blockIdx.y * 32, j0 = blockIdx.x * 32;
    int zs = blockIdx.z * 246;
    int ze = zs + 246 < Nn ? zs + 246 : Nn;
    float2 acc[2][2] = {};
    for (int k0 = zs; k0 < ze; k0 += 32) {
        #pragma unroll
        for (int rep = 0; rep < 4; ++rep) {
            int idx = t + rep * 256;
            int rr = idx >> 5, cc = idx & 31;
            int gk = k0 + cc;
            int gi = i0 + rr, gj = j0 + rr;
            float2 a = make_float2(0.f, 0.f), b = make_float2(0.f, 0.f);
            if (gk < ze) {
                if (gi < Mm) a = make_float2(pr[(size_t)gi * Nn + gk], pi[(size_t)gi * Nn + gk]);
                if (gj < Mm) b = make_float2(pr[(size_t)gj * Nn + gk], pi[(size_t)gj * Nn + gk]);
            }
            As[rr][cc] = a; Bs[rr][cc] = b;
        }
        __syncthreads();
        #pragma unroll 8
        for (int kk = 0; kk < 32; ++kk) {
            float2 a0 = As[ty * 2][kk], a1 = As[ty * 2 + 1][kk];
            float2 b0 = Bs[tx * 2][kk], b1 = Bs[tx * 2 + 1][kk];
            #define GMAC(qq, aa, bb) \
                qq.x = fmaf(aa.x, bb.x, qq.x); qq.x = fmaf(aa.y, bb.y, qq.x); \
                qq.y = fmaf(aa.y, bb.x, qq.y); qq.y = fmaf(-aa.x, bb.y, qq.y);
            GMAC(acc[0][0], a0, b0) GMAC(acc[0][1], a0, b1)
            GMAC(acc[1][0], a1, b0) GMAC(acc[1][1], a1, b1)
            #undef GMAC
        }
        __syncthreads();
    }
    #pragma unroll
    for (int i = 0; i < 2; ++i) {
        int gi = i0 + ty * 2 + i;
        #pragma unroll
        for (int j = 0; j < 2; ++j) {
            int gj = j0 + tx * 2 + j;
            if (gi < Mm && gj < Mm) {
                atomicAdd(&G[gi * Mm + gj].x, acc[i][j].x);
                atomicAdd(&G[gi * Mm + gj].y, acc[i][j].y);
            }
        }
    }
}

// ---------------- frobz: Frobenius^2 of src + zero dst (fused with next-stage memset) ----
__global__ void frobz_kernel(const float2* __restrict__ H, float* __restrict__ slot,
                             float2* __restrict__ dst, int n) {
    int idx = blockIdx.x * blockDim.x + threadIdx.x;
    int stride = gridDim.x * blockDim.x;
    float s = 0.f;
    for (int i = idx; i < n; i += stride) {
        float2 v = H[i];
        s = fmaf(v.x, v.x, s);
        s = fmaf(v.y, v.y, s);
        dst[i] = make_float2(0.f, 0.f);
    }
    #pragma unroll
    for (int o = 32; o > 0; o >>= 1) s += __shfl_down(s, o, 64);
    __shared__ float wsum[4];
    int lane = threadIdx.x & 63, wv = threadIdx.x >> 6;
    if (lane == 0) wsum[wv] = s;
    __syncthreads();
    if (threadIdx.x == 0) atomicAdd(slot, wsum[0] + wsum[1] + wsum[2] + wsum[3]);
}

// ---------------- C += (A/||A||_F)^2 partial (split-K, C pre-zeroed) ----------------
__global__ void sqmm_kernel(const float2* __restrict__ A, float2* __restrict__ C,
                            const float* __restrict__ fslot) {
    __shared__ float2 As[32][33];
    __shared__ float2 Bs[32][33];
    float inv = 1.0f / fslot[0];
    int tx = threadIdx.x, ty = threadIdx.y;
    int t = ty * 16 + tx;
    int r0 = blockIdx.y * 32, c0 = blockIdx.x * 32;
    int zs = blockIdx.z * 80;
    int ze = zs + 80 < Mm ? zs + 80 : Mm;
    float2 acc[2][2] = {};
    for (int k0 = zs; k0 < ze; k0 += 32) {
        #pragma unroll
        for (int i = 0; i < 4; ++i) {
            int idx = t + i * 256;
            int rr = idx >> 5, cc = idx & 31;
            int gr = r0 + rr, gk = k0 + cc;
            As[rr][cc] = (gr < Mm && gk < ze) ? A[gr * Mm + gk] : make_float2(0.f, 0.f);
            int gk2 = k0 + rr, gc = c0 + cc;
            Bs[rr][cc] = (gk2 < ze && gc < Mm) ? A[gk2 * Mm + gc] : make_float2(0.f, 0.f);
        }
        __syncthreads();
        #pragma unroll 8
        for (int kk = 0; kk < 32; ++kk) {
            float2 a0 = As[ty * 2][kk], a1 = As[ty * 2 + 1][kk];
            float2 b0 = Bs[kk][tx * 2], b1 = Bs[kk][tx * 2 + 1];
            cmac(acc[0][0], a0, b0); cmac(acc[0][1], a0, b1);
            cmac(acc[1][0], a1, b0); cmac(acc[1][1], a1, b1);
        }
        __syncthreads();
    }
    #pragma unroll
    for (int i = 0; i < 2; ++i) {
        int gr = r0 + ty * 2 + i;
        #pragma unroll
        for (int j = 0; j < 2; ++j) {
            int gc = c0 + tx * 2 + j;
            if (gr < Mm && gc < Mm) {
                atomicAdd(&C[gr * Mm + gc].x, acc[i][j].x * inv);
                atomicAdd(&C[gr * Mm + gc].y, acc[i][j].y * inv);
            }
        }
    }
}

// ---------------- Rayleigh, parallelized: ray1 v=H*ones; ray2 num/den; ray3 sc ----------
__global__ void ray1_kernel(const float2* __restrict__ H, float2* __restrict__ v) {
    int t = blockIdx.x;          // row 0..Mm-1
    int k = threadIdx.x;         // 256 threads
    float sx = 0.f, sy = 0.f;
    for (int j = k; j < Mm; j += 256) {
        float2 h = H[(size_t)t * Mm + j];
        sx += h.x; sy += h.y;
    }
    #pragma unroll
    for (int o = 32; o > 0; o >>= 1) { sx += __shfl_down(sx, o, 64); sy += __shfl_down(sy, o, 64); }
    __shared__ float wx[4], wy[4];
    int lane = k & 63, wv = k >> 6;
    if (lane == 0) { wx[wv] = sx; wy[wv] = sy; }
    __syncthreads();
    if (k == 0) v[t] = make_float2(wx[0] + wx[1] + wx[2] + wx[3],
                                   wy[0] + wy[1] + wy[2] + wy[3]);
}

__global__ void ray2_kernel(const float2* __restrict__ G, const float2* __restrict__ v,
                            float* __restrict__ slots) {
    int t = blockIdx.x;
    int k0 = threadIdx.x;
    float ux = 0.f, uy = 0.f;
    for (int k = k0; k < Mm; k += 256) {
        float2 g = G[(size_t)k * Mm + t];
        float2 vk = v[k];
        ux = fmaf(g.x, vk.x, ux); ux = fmaf(g.y, vk.y, ux);
        uy = fmaf(g.x, vk.y, uy); uy = fmaf(-g.y, vk.x, uy);
    }
    #pragma unroll
    for (int o = 32; o > 0; o >>= 1) { ux += __shfl_down(ux, o, 64); uy += __shfl_down(uy, o, 64); }
    __shared__ float wx[4], wy[4];
    int lane = k0 & 63, wv = k0 >> 6;
    if (lane == 0) { wx[wv] = ux; wy[wv] = uy; }
    __syncthreads();
    if (k0 == 0) {
        float sux = wx[0] + wx[1] + wx[2] + wx[3];
        float suy = wy[0] + wy[1] + wy[2] + wy[3];
        float2 vt = v[t];
        atomicAdd(&slots[16], vt.x * sux + vt.y * suy);   // num partial
        atomicAdd(&slots[17], vt.x * vt.x + vt.y * vt.y); // den partial
    }
}

__global__ void ray3_kernel(const float* __restrict__ slots, float* __restrict__ sc) {
    float step = slots[17] / slots[16];   // 1/lambda = den/num
    sc[0] = step;
    sc[1] = 0.1f * step;
}

// ---------------- qpack: M = I - step*Q  (identity folded onto diagonal)
// 2x4 micro-tile; c mapped as c0 + j*16 + tx so lanes read Pc at stride-1 float2
// (2-way bank alias = free). Full grid (Hermitian mirror-write variant measured
// slower: scattered swizzled mirror stores cost more than the saved FLOPs).
__global__ void qpack_kernel(const float* __restrict__ pr, const float* __restrict__ pi,
                             unsigned int* __restrict__ Bu, const float* __restrict__ sc) {
    __shared__ float2 Pn[16][33];
    __shared__ float2 Pc[16][65];
    float nstep = -sc[0];
    int t = threadIdx.x;
    int tx = t & 15, ty = t >> 4;
    int n0 = blockIdx.x * 32, c0 = blockIdx.y * 64;
    float2 q[2][4] = {};
    for (int m0 = 0; m0 < Mm; m0 += 16) {
        #pragma unroll
        for (int rep = 0; rep < 6; ++rep) {
            int idx = t + rep * 256;
            if (idx < 512) {
                int mm = idx >> 5, col = idx & 31;
                int gm = m0 + mm;
                float2 a = make_float2(0.f, 0.f);
                if (gm < Mm && n0 + col < Nn)
                    a = make_float2(pr[(size_t)gm * Nn + n0 + col], pi[(size_t)gm * Nn + n0 + col]);
                Pn[mm][col] = a;
            } else {
                int idx2 = idx - 512;
                int mm = idx2 >> 6, col = idx2 & 63;
                int gm = m0 + mm;
                float2 b = make_float2(0.f, 0.f);
                if (gm < Mm && c0 + col < Nn)
                    b = make_float2(pr[(size_t)gm * Nn + c0 + col], pi[(size_t)gm * Nn + c0 + col]);
                Pc[mm][col] = b;
            }
        }
        __syncthreads();
        #pragma unroll
        for (int mm = 0; mm < 16; ++mm) {
            float2 a0 = Pn[mm][ty * 2], a1 = Pn[mm][ty * 2 + 1];
            float2 b0 = Pc[mm][tx], b1 = Pc[mm][16 + tx];
            float2 b2 = Pc[mm][32 + tx], b3 = Pc[mm][48 + tx];
            // q += a * conj(b)
            #define QMAC(qq, aa, bb) \
                qq.x = fmaf(aa.x, bb.x, qq.x); qq.x = fmaf(aa.y, bb.y, qq.x); \
                qq.y = fmaf(aa.y, bb.x, qq.y); qq.y = fmaf(-aa.x, bb.y, qq.y);
            QMAC(q[0][0], a0, b0) QMAC(q[0][1], a0, b1) QMAC(q[0][2], a0, b2) QMAC(q[0][3], a0, b3)
            QMAC(q[1][0], a1, b0) QMAC(q[1][1], a1, b1) QMAC(q[1][2], a1, b2) QMAC(q[1][3], a1, b3)
            #undef QMAC
        }
        __syncthreads();
    }
    #pragma unroll
    for (int i = 0; i < 2; ++i) {
        int n = n0 + ty * 2 + i;
        #pragma unroll
        for (int j = 0; j < 4; ++j) {
            int c = c0 + j * 16 + tx;
            if (n < Nn && c < Nn) {
                // M = I - step*Q : identity folds onto the real diagonal
                float MR = fmaf(nstep, q[i][j].x, (n == c) ? 1.0f : 0.0f);
                float MI = nstep * q[i][j].y;
                unsigned short hR = f16bits(MR);
                unsigned short hI = f16bits(MI);
                unsigned short nhI = hI ^ 0x8000u;
                int jr = ((c >> 5) * 64) + (c & 31);
                Bu[swzB(jr, n)]      = (unsigned)hR | ((unsigned)nhI << 16);  // Re row
                Bu[swzB(jr + 32, n)] = (unsigned)hI | ((unsigned)hR << 16);   // Im row
            }
        }
    }
}

// ---------------- rpack: r -> f16 pairs in A2 layout (K=640) ----------------
__global__ void rpack_kernel(const float* __restrict__ rr, const float* __restrict__ ri,
                             unsigned int* __restrict__ rp16) {
    int b = blockIdx.x * 256 + threadIdx.x;
    int m = blockIdx.y;
    rp16[swzA2(b, m)] = (unsigned)f16bits(rr[(size_t)b * Mm + m]) |
                        ((unsigned)f16bits(ri[(size_t)b * Mm + m]) << 16);
}

// ---------------- ppack2: B2 = -step*conj(phi) pack, K=640 layout ----------------
__global__ void ppack2_kernel(const float* __restrict__ pr, const float* __restrict__ pi,
                              unsigned int* __restrict__ B2u, const float* __restrict__ sc) {
    int n = blockIdx.x * 256 + threadIdx.x;
    int m = blockIdx.y;
    if (n >= Nn) return;
    float s = sc[0];
    float xr = pr[(size_t)m * Nn + n], xi = pi[(size_t)m * Nn + n];
    unsigned short x = f16bits(-s * xr), y = f16bits(-s * xi);
    int jr2 = ((n >> 5) * 64) + (n & 31);
    B2u[swzB2(jr2, m)]      = (unsigned)x | ((unsigned)y << 16);
    B2u[swzB2(jr2 + 32, m)] = (unsigned)(y ^ 0x8000u) | ((unsigned)x << 16);
}

// ---------------- rphi_mfma: rph16 = f16(step * r * conj(phi)) AND w1 = shrink(rph) -----
// Fuses ISTA iteration 0: with w0 = 0 the first GEMM's acc is exactly zero, so
// w1 = shrink(rph). Applying shrink to the f16-quantized rph value here is
// bit-identical to the old it=0 dispatch (which added exact-zero acc to f16lo(ru)).
// Grid covers all 4096 rows x 1024 complex cols. Single-buffered, implicit TLP.
__global__ __launch_bounds__(256, 2) void rphi_mfma_kernel(
    const _Float16* __restrict__ rp16, const _Float16* __restrict__ B2,
    unsigned int* __restrict__ rph16, unsigned int* __restrict__ w1o,
    const float* __restrict__ sc) {
    __shared__ _Float16 As[8192];
    __shared__ _Float16 Bs[8192];
    int tid = threadIdx.x;
    int lane = tid & 63, wv = tid >> 6;
    int wm = wv & 1, wn = wv >> 1;
    int bblk = blockIdx.x, nblk = blockIdx.y;
    int l31 = lane & 31, lh = lane >> 5;

    f32x16 acc[2][2] = {};

    for (int kt = 0; kt < 10; ++kt) {
        #pragma unroll
        for (int c = 0; c < 4; ++c) {
            int u = c * 256 + tid;
            const char* ga = (const char*)rp16 + (((size_t)(bblk * 10 + kt)) * 1024 + u) * 16;
            load_lds16(ga, &As[(size_t)(c * 256 + wv * 64) * 8]);
            const char* gb = (const char*)B2 + (((size_t)(nblk * 10 + kt)) * 1024 + u) * 16;
            load_lds16(gb, &Bs[(size_t)(c * 256 + wv * 64) * 8]);
        }
        __syncthreads();
        #pragma unroll
        for (int s = 0; s < 4; ++s) {
            int kq = s * 2 + lh;
            f16x8 af[2], bfr[2];
            #pragma unroll
            for (int mt = 0; mt < 2; ++mt)
                af[mt] = *reinterpret_cast<const f16x8*>(
                    &As[(size_t)(kq * 128 + wm * 64 + mt * 32 + l31) * 8]);
            #pragma unroll
            for (int nt = 0; nt < 2; ++nt)
                bfr[nt] = *reinterpret_cast<const f16x8*>(
                    &Bs[(size_t)(kq * 128 + wn * 64 + nt * 32 + l31) * 8]);
            #pragma unroll
            for (int mt = 0; mt < 2; ++mt)
                #pragma unroll
                for (int nt = 0; nt < 2; ++nt)
                    acc[mt][nt] = __builtin_amdgcn_mfma_f32_32x32x16_f16(af[mt], bfr[nt], acc[mt][nt], 0, 0, 0);
        }
        __syncthreads();
    }

    float thr = sc[1];
    int b0 = bblk * 128;
    int c = nblk * 64 + wn * 32 + l31;
    #pragma unroll
    for (int mt = 0; mt < 2; ++mt) {
        #pragma unroll
        for (int reg = 0; reg < 16; ++reg) {
            int row = b0 + wm * 64 + mt * 32 + ((reg & 3) + 8 * (reg >> 2) + 4 * lh);
            unsigned int ru = (unsigned)f16bits(-acc[mt][0][reg]) |
                              ((unsigned)f16bits(-acc[mt][1][reg]) << 16);
            rph16[(size_t)row * NCP + c] = ru;
            // fused ISTA it=0: w1 = shrink(rph) on the f16-quantized value
            float zr = f16lo(ru);
            float zi = f16hi(ru);
            float mag = sqrtf(zr * zr + zi * zi);
            float nm = mag - thr;
            float f = (nm > 0.f) ? (nm / mag) : 0.f;
            w1o[swzA(row, c)] = (unsigned)f16bits(zr * f) | ((unsigned)f16bits(zi * f) << 16);
        }
    }
}

// ---------------- main ISTA iteration (ista9): 512-thr block, tile 128x128 -------------
// 8 waves (2m x 4n), wave tile 64 rows x 32 complex cols. Static dbuf (96 KB LDS),
// counted vmcnt(6) + raw barriers. XCD-tiled block remap: each XCD owns an 8x4 tile of
// the 32x8 (rowgroup x colgroup) grid -> L2-local wfi AND Bq.
// K-loop runs 31 tiles (not 32): complex cols 992..1023 are structural zeros in both
// w and Bq (Nn=984 + padding), so k-tile 31 contributes exactly 0 and is skipped.
// Bq packs (I - step*Q): epilogue z = acc + rph.
__global__ __launch_bounds__(512) void ista9_kernel(
    const _Float16* __restrict__ wfi, const _Float16* __restrict__ Bq,
    unsigned int* __restrict__ wfo,
    const unsigned int* __restrict__ rph16,
    const float* __restrict__ sc, float* __restrict__ out, int last) {
    __shared__ _Float16 As0[8192], As1[8192];           // A k-tile dbuf (16 KB each)
    __shared__ _Float16 Bs0[2][8192], Bs1[2][8192];     // B k-tile dbuf (2 x 64-col slabs)
    int tid = threadIdx.x;
    int lane = tid & 63, wv = tid >> 6;          // wv 0..7
    int wm = wv >> 2, wn = wv & 3;               // wm: row half; wn: 32-col group 0..3
    int id = blockIdx.x;
    int x = id & 7;                              // XCD (round-robin dispatch)
    int n = id >> 3;                             // 0..31 within XCD
    int bblk = (x & 3) * 8 + (n & 7);            // 0..31 (128-row group) ; 8 per XCD
    int nb2  = (x >> 2) * 4 + (n >> 3);          // 0..7  (128-col group) ; 4 per XCD
    int l31 = lane & 31, lh = lane >> 5;
    int slab = wn >> 1, chg = wn & 1;            // B slab + 32-col group within slab

    f32x16 acc[2][2] = {};                       // [mt][nt: 0=Re,1=Im]

    const char* gA  = (const char*)wfi + (size_t)bblk * 32 * 1024 * 16;
    const char* gB0 = (const char*)Bq + (size_t)(nb2 * 2 + 0) * 32 * 1024 * 16;
    const char* gB1 = (const char*)Bq + (size_t)(nb2 * 2 + 1) * 32 * 1024 * 16;

    // stage one k-tile: A 1024 chunks + B 2x1024 chunks, 512 threads -> 6 loads/thread
    #define STAGE9(kt, Ad, Bd)                                                        \
        {                                                                             \
            _Float16* Ap = (Ad);                                                      \
            _Float16* Bp0 = &(Bd)[0][0];                                              \
            _Float16* Bp1 = &(Bd)[1][0];                                              \
            _Pragma("unroll")                                                         \
            for (int cc = 0; cc < 2; ++cc) {                                          \
                int u = cc * 512 + tid;                                               \
                size_t ldst = (size_t)(cc * 512 + wv * 64) * 8;                       \
                load_lds16(gA + ((size_t)(kt) * 1024 + u) * 16, &Ap[ldst]);           \
                load_lds16(gB0 + ((size_t)(kt) * 1024 + u) * 16, &Bp0[ldst]);         \
                load_lds16(gB1 + ((size_t)(kt) * 1024 + u) * 16, &Bp1[ldst]);         \
            }                                                                         \
        }

    #define COMPUTE9(Asrc, Bsrc)                                                      \
        {                                                                             \
            _Pragma("unroll")                                                         \
            for (int s = 0; s < 4; ++s) {                                             \
                int kq = s * 2 + lh;                                                  \
                f16x8 af[2], bf[2];                                                   \
                _Pragma("unroll")                                                     \
                for (int mt = 0; mt < 2; ++mt)                                        \
                    af[mt] = *reinterpret_cast<const f16x8*>(                         \
                        &(Asrc)[(size_t)(kq * 128 + wm * 64 + mt * 32 + l31) * 8]);   \
                _Pragma("unroll")                                                     \
                for (int nt = 0; nt < 2; ++nt)                                        \
                    bf[nt] = *reinterpret_cast<const f16x8*>(                         \
                        &(Bsrc)[slab][(size_t)(kq * 128 + chg * 64 + nt * 32 + l31) * 8]); \
                _Pragma("unroll")                                                     \
                for (int mt = 0; mt < 2; ++mt)                                        \
                    _Pragma("unroll")                                                 \
                    for (int nt = 0; nt < 2; ++nt)                                    \
                        acc[mt][nt] = __builtin_amdgcn_mfma_f32_32x32x16_f16(         \
                            af[mt], bf[nt], acc[mt][nt], 0, 0, 0);                    \
            }                                                                         \
        }

    STAGE9(0, As0, Bs0);
    for (int kt = 0; kt < 30; kt += 2) {
        STAGE9(kt + 1, As1, Bs1);
        asm volatile("s_waitcnt vmcnt(6)" ::: "memory");   // tile kt landed; kt+1's 6 in flight
        __builtin_amdgcn_s_barrier();
        COMPUTE9(As0, Bs0);
        __builtin_amdgcn_s_barrier();
        STAGE9(kt + 2, As0, Bs0);                          // max kt+2 = 30 (in bounds)
        asm volatile("s_waitcnt vmcnt(6)" ::: "memory");   // tile kt+1 landed
        __builtin_amdgcn_s_barrier();
        COMPUTE9(As1, Bs1);
        __builtin_amdgcn_s_barrier();
    }
    // tiles 0..29 computed; tile 30 staged into As0/Bs0 with 6 loads outstanding
    asm volatile("s_waitcnt vmcnt(0)" ::: "memory");
    __builtin_amdgcn_s_barrier();
    COMPUTE9(As0, Bs0);
    // tile 31 skipped: structurally zero (w and Bq cols 992..1023 are padding zeros)
    #undef STAGE9
    #undef COMPUTE9

    float thr = sc[1];
    int b0 = bblk * 128;
    int c = nb2 * 128 + wn * 32 + l31;   // complex col for this lane
    #pragma unroll
    for (int mt = 0; mt < 2; ++mt) {
        #pragma unroll
        for (int reg = 0; reg < 16; ++reg) {
            int row = b0 + wm * 64 + mt * 32 + ((reg & 3) + 8 * (reg >> 2) + 4 * lh);
            unsigned int ru = rph16[(size_t)row * NCP + c];
            float zr = acc[mt][0][reg] + f16lo(ru);
            float zi = acc[mt][1][reg] + f16hi(ru);
            float mag = sqrtf(zr * zr + zi * zi);
            float nm = mag - thr;
            float f = (nm > 0.f) ? (nm / mag) : 0.f;
            wfo[swzA(row, c)] = (unsigned)f16bits(zr * f) | ((unsigned)f16bits(zi * f) << 16);
            if (last && c < Nn) out[(size_t)row * Nn + c] = fmaxf(nm, 0.f);
        }
    }
}

extern "C" void kernel_launch(void* const* d_in, const int* in_sizes, int n_in,
                              void* d_out, int out_size, void* d_ws, size_t ws_size,
                              hipStream_t stream) {
    const float* rr = (const float*)d_in[0];
    const float* ri = (const float*)d_in[1];
    const float* pr = (const float*)d_in[2];
    const float* pi = (const float*)d_in[3];
    float* out = (float*)d_out;

    char* ws = (char*)d_ws;
    size_t off = 0;
    _Float16* wf0 = (_Float16*)(ws + off); off += (size_t)Bb * KA * sizeof(_Float16);   // 16 MB
    _Float16* wf1 = (_Float16*)(ws + off); off += (size_t)Bb * KA * sizeof(_Float16);   // 16 MB
    _Float16* Bq  = (_Float16*)(ws + off); off += (size_t)2048 * 2048 * sizeof(_Float16); // 8 MB
    unsigned int* rph16 = (unsigned int*)(ws + off); off += (size_t)Bb * NCP * 4;       // 16 MB
    _Float16* rp16 = (_Float16*)(ws + off); off += (size_t)Bb * 640 * sizeof(_Float16);   // 5.2 MB
    _Float16* B2  = (_Float16*)(ws + off); off += (size_t)2048 * 640 * sizeof(_Float16);  // 2.6 MB
    float2* G = (float2*)(ws + off);     off += (size_t)Mm * Mm * sizeof(float2);
    float2* H1 = (float2*)(ws + off);    off += (size_t)Mm * Mm * sizeof(float2);
    float2* H2 = (float2*)(ws + off);    off += (size_t)Mm * Mm * sizeof(float2);
    float2* vvec = (float2*)(ws + off);  off += (size_t)Mm * sizeof(float2);
    float* slots = (float*)(ws + off);   off += 64 * sizeof(float);
    float* sc = slots + 32;

    // wf0 memset dropped: it=1 (first ista dispatch) writes wf0 before anything reads it
    (void)hipMemsetAsync(Bq, 0, (size_t)2048 * 2048 * sizeof(_Float16), stream);
    (void)hipMemsetAsync(rp16, 0, (size_t)Bb * 640 * sizeof(_Float16), stream);
    (void)hipMemsetAsync(B2, 0, (size_t)2048 * 640 * sizeof(_Float16), stream);
    (void)hipMemsetAsync(slots, 0, 64 * sizeof(float), stream);
    (void)hipMemsetAsync(G, 0, (size_t)Mm * Mm * sizeof(float2), stream);

    // spectral norm chain on G (306x306): G -> normalize+square x KSQ -> Rayleigh
    gram_kernel<<<dim3(10, 10, 4), dim3(16, 16), 0, stream>>>(pr, pi, G);
    float2* bufs[2] = { H1, H2 };
    const float2* src = G;
    for (int s = 0; s < KSQ; ++s) {
        float2* dst = bufs[s & 1];
        frobz_kernel<<<128, 256, 0, stream>>>(src, slots + s, dst, Mm * Mm);
        sqmm_kernel<<<dim3(10, 10, 4), dim3(16, 16), 0, stream>>>(src, dst, slots + s);
        src = dst;
    }
    ray1_kernel<<<Mm, 256, 0, stream>>>(src, vvec);
    ray2_kernel<<<Mm, 256, 0, stream>>>(G, vvec, slots);
    ray3_kernel<<<1, 1, 0, stream>>>(slots, sc);

    // precompute: packed operator (I - step*Q f16), r pack, -step*conj(phi) pack,
    // rphi MFMA (also produces w1 = shrink(rph), i.e. ISTA iteration 0)
    qpack_kernel<<<dim3(31, 16), 256, 0, stream>>>(pr, pi, (unsigned int*)Bq, sc);
    rpack_kernel<<<dim3(16, Mm), 256, 0, stream>>>(rr, ri, (unsigned int*)rp16);
    ppack2_kernel<<<dim3(4, Mm), 256, 0, stream>>>(pr, pi, (unsigned int*)B2, sc);
    rphi_mfma_kernel<<<dim3(32, 16), 256, 0, stream>>>(rp16, B2, rph16,
                                                       (unsigned int*)wf1, sc);

    // ISTA main loop: iterations 1..49 (it=0 fused into rphi), f16 state ping-pong
    _Float16* wbuf[2] = { wf0, wf1 };
    for (int it = 1; it < ITERS; ++it) {
        ista9_kernel<<<256, 512, 0, stream>>>(
            wbuf[it & 1], Bq, (unsigned int*)wbuf[(it + 1) & 1], rph16, sc, out,
            it == ITERS - 1 ? 1 : 0);
    }
}

// Round 14
// 2732.930 us; speedup vs baseline: 3.0772x; 1.0151x over previous
//
#include <hip/hip_runtime.h>
#include <math.h>

#define Bb 4096
#define Mm 306
#define Nn 984      // complex cols
#define NCP 1024    // padded complex cols
#define KA 2048     // w real k-cols (padded)
#define ITERS 50
#define KSQ 9       // squaring stages: G^(2^9) then Rayleigh

typedef _Float16 f16x8 __attribute__((ext_vector_type(8)));
typedef float f32x16 __attribute__((ext_vector_type(16)));

__device__ __forceinline__ void cmac(float2& c, const float2 a, const float2 b) {
    c.x = fmaf(a.x, b.x, c.x);
    c.x = fmaf(-a.y, b.y, c.x);
    c.y = fmaf(a.x, b.y, c.y);
    c.y = fmaf(a.y, b.x, c.y);
}

__device__ __forceinline__ unsigned short f16bits(float v) {
    union { _Float16 h; unsigned short u; } cv;
    cv.h = (_Float16)v;
    return cv.u;
}
__device__ __forceinline__ float f16lo(unsigned int u) {
    union { unsigned short s; _Float16 h; } cv; cv.s = (unsigned short)(u & 0xffffu);
    return (float)cv.h;
}
__device__ __forceinline__ float f16hi(unsigned int u) {
    union { unsigned short s; _Float16 h; } cv; cv.s = (unsigned short)(u >> 16);
    return (float)cv.h;
}

__device__ __forceinline__ void load_lds16(const void* g, void* l) {
    __builtin_amdgcn_global_load_lds((const __attribute__((address_space(1))) void*)g,
                                     (__attribute__((address_space(3))) void*)l, 16, 0, 0);
}

// ---- swizzled uint (4B) index, w/A operand (K=2048: 32 ktiles), (row b, complex col c) --
__device__ __forceinline__ size_t swzA(int b, int c) {
    return ((size_t)(((b >> 7) * 32 + (c >> 5)) * 1024 + ((c >> 2) & 7) * 128 + (b & 127))) * 4 + (c & 3);
}
// ---- B operand (Q op, K=2048: 32 ktiles), (row jr, uint col q) ----
__device__ __forceinline__ size_t swzB(int jr, int q) {
    return ((size_t)(((jr >> 7) * 32 + (q >> 5)) * 1024 + ((q >> 2) & 7) * 128 + (jr & 127))) * 4 + (q & 3);
}
// ---- A2 operand (r pack, K=640: 10 ktiles), (row b, complex col c<320) ----
__device__ __forceinline__ size_t swzA2(int b, int c) {
    return ((size_t)(((b >> 7) * 10 + (c >> 5)) * 1024 + ((c >> 2) & 7) * 128 + (b & 127))) * 4 + (c & 3);
}
// ---- B2 operand (-step*conj(phi) pack, K=640: 10 ktiles), (row jr, uint col q<320) ----
__device__ __forceinline__ size_t swzB2(int jr, int q) {
    return ((size_t)(((jr >> 7) * 10 + (q >> 5)) * 1024 + ((q >> 2) & 7) * 128 + (jr & 127))) * 4 + (q & 3);
}

// ---------------- G = phi * phi^H  (306x306 complex), tiled + split-K ----------------
__global__ void gram_kernel(const float* __restrict__ pr, const float* __restrict__ pi,
                            float2* __restrict__ G) {
    __shared__ float2 As[32][33];
    __shared__ float2 Bs[32][33];
    int tx = threadIdx.x, ty = threadIdx.y;
    int t = ty * 16 + tx;
    int i0 = blockIdx.y * 32, j0 = blockIdx.x * 32;
    int zs = blockIdx.z * 246;
    int ze = zs + 246 < Nn ? zs + 246 : Nn;
    float2 acc[2][2] = {};
    for (int k0 = zs; k0 < ze; k0 += 32) {
        #pragma unroll
        for (int rep = 0; rep < 4; ++rep) {
            int idx = t + rep * 256;
            int rr = idx >> 5, cc = idx & 31;
            int gk = k0 + cc;
            int gi = i0 + rr, gj = j0 + rr;
            float2 a = make_float2(0.f, 0.f), b = make_float2(0.f, 0.f);
            if (gk < ze) {
                if (gi < Mm) a = make_float2(pr[(size_t)gi * Nn + gk], pi[(size_t)gi * Nn + gk]);
                if (gj < Mm) b = make_float2(pr[(size_t)gj * Nn + gk], pi[(size_t)gj * Nn + gk]);
            }
            As[rr][cc] = a; Bs[rr][cc] = b;
        }
        __syncthreads();
        #pragma unroll 8
        for (int kk = 0; kk < 32; ++kk) {
            float2 a0 = As[ty * 2][kk], a1 = As[ty * 2 + 1][kk];
            float2 b0 = Bs[tx * 2][kk], b1 = Bs[tx * 2 + 1][kk];
            #define GMAC(qq, aa, bb) \
                qq.x = fmaf(aa.x, bb.x, qq.x); qq.x = fmaf(aa.y, bb.y, qq.x); \
                qq.y = fmaf(aa.y, bb.x, qq.y); qq.y = fmaf(-aa.x, bb.y, qq.y);
            GMAC(acc[0][0], a0, b0) GMAC(acc[0][1], a0, b1)
            GMAC(acc[1][0], a1, b0) GMAC(acc[1][1], a1, b1)
            #undef GMAC
        }
        __syncthreads();
    }
    #pragma unroll
    for (int i = 0; i < 2; ++i) {
        int gi = i0 + ty * 2 + i;
        #pragma unroll
        for (int j = 0; j < 2; ++j) {
            int gj = j0 + tx * 2 + j;
            if (gi < Mm && gj < Mm) {
                atomicAdd(&G[gi * Mm + gj].x, acc[i][j].x);
                atomicAdd(&G[gi * Mm + gj].y, acc[i][j].y);
            }
        }
    }
}

// ---------------- frobz: Frobenius^2 of src + zero dst (fused with next-stage memset) ----
__global__ void frobz_kernel(const float2* __restrict__ H, float* __restrict__ slot,
                             float2* __restrict__ dst, int n) {
    int idx = blockIdx.x * blockDim.x + threadIdx.x;
    int stride = gridDim.x * blockDim.x;
    float s = 0.f;
    for (int i = idx; i < n; i += stride) {
        float2 v = H[i];
        s = fmaf(v.x, v.x, s);
        s = fmaf(v.y, v.y, s);
        dst[i] = make_float2(0.f, 0.f);
    }
    #pragma unroll
    for (int o = 32; o > 0; o >>= 1) s += __shfl_down(s, o, 64);
    __shared__ float wsum[4];
    int lane = threadIdx.x & 63, wv = threadIdx.x >> 6;
    if (lane == 0) wsum[wv] = s;
    __syncthreads();
    if (threadIdx.x == 0) atomicAdd(slot, wsum[0] + wsum[1] + wsum[2] + wsum[3]);
}

// ---------------- C += (A/||A||_F)^2 partial (split-K, C pre-zeroed) ----------------
__global__ void sqmm_kernel(const float2* __restrict__ A, float2* __restrict__ C,
                            const float* __restrict__ fslot) {
    __shared__ float2 As[32][33];
    __shared__ float2 Bs[32][33];
    float inv = 1.0f / fslot[0];
    int tx = threadIdx.x, ty = threadIdx.y;
    int t = ty * 16 + tx;
    int r0 = blockIdx.y * 32, c0 = blockIdx.x * 32;
    int zs = blockIdx.z * 80;
    int ze = zs + 80 < Mm ? zs + 80 : Mm;
    float2 acc[2][2] = {};
    for (int k0 = zs; k0 < ze; k0 += 32) {
        #pragma unroll
        for (int i = 0; i < 4; ++i) {
            int idx = t + i * 256;
            int rr = idx >> 5, cc = idx & 31;
            int gr = r0 + rr, gk = k0 + cc;
            As[rr][cc] = (gr < Mm && gk < ze) ? A[gr * Mm + gk] : make_float2(0.f, 0.f);
            int gk2 = k0 + rr, gc = c0 + cc;
            Bs[rr][cc] = (gk2 < ze && gc < Mm) ? A[gk2 * Mm + gc] : make_float2(0.f, 0.f);
        }
        __syncthreads();
        #pragma unroll 8
        for (int kk = 0; kk < 32; ++kk) {
            float2 a0 = As[ty * 2][kk], a1 = As[ty * 2 + 1][kk];
            float2 b0 = Bs[kk][tx * 2], b1 = Bs[kk][tx * 2 + 1];
            cmac(acc[0][0], a0, b0); cmac(acc[0][1], a0, b1);
            cmac(acc[1][0], a1, b0); cmac(acc[1][1], a1, b1);
        }
        __syncthreads();
    }
    #pragma unroll
    for (int i = 0; i < 2; ++i) {
        int gr = r0 + ty * 2 + i;
        #pragma unroll
        for (int j = 0; j < 2; ++j) {
            int gc = c0 + tx * 2 + j;
            if (gr < Mm && gc < Mm) {
                atomicAdd(&C[gr * Mm + gc].x, acc[i][j].x * inv);
                atomicAdd(&C[gr * Mm + gc].y, acc[i][j].y * inv);
            }
        }
    }
}

// ---------------- Rayleigh, parallelized: ray1 v=H*ones; ray2 num/den; ray3 sc ----------
__global__ void ray1_kernel(const float2* __restrict__ H, float2* __restrict__ v) {
    int t = blockIdx.x;          // row 0..Mm-1
    int k = threadIdx.x;         // 256 threads
    float sx = 0.f, sy = 0.f;
    for (int j = k; j < Mm; j += 256) {
        float2 h = H[(size_t)t * Mm + j];
        sx += h.x; sy += h.y;
    }
    #pragma unroll
    for (int o = 32; o > 0; o >>= 1) { sx += __shfl_down(sx, o, 64); sy += __shfl_down(sy, o, 64); }
    __shared__ float wx[4], wy[4];
    int lane = k & 63, wv = k >> 6;
    if (lane == 0) { wx[wv] = sx; wy[wv] = sy; }
    __syncthreads();
    if (k == 0) v[t] = make_float2(wx[0] + wx[1] + wx[2] + wx[3],
                                   wy[0] + wy[1] + wy[2] + wy[3]);
}

__global__ void ray2_kernel(const float2* __restrict__ G, const float2* __restrict__ v,
                            float* __restrict__ slots) {
    int t = blockIdx.x;
    int k0 = threadIdx.x;
    float ux = 0.f, uy = 0.f;
    for (int k = k0; k < Mm; k += 256) {
        float2 g = G[(size_t)k * Mm + t];
        float2 vk = v[k];
        ux = fmaf(g.x, vk.x, ux); ux = fmaf(g.y, vk.y, ux);
        uy = fmaf(g.x, vk.y, uy); uy = fmaf(-g.y, vk.x, uy);
    }
    #pragma unroll
    for (int o = 32; o > 0; o >>= 1) { ux += __shfl_down(ux, o, 64); uy += __shfl_down(uy, o, 64); }
    __shared__ float wx[4], wy[4];
    int lane = k0 & 63, wv = k0 >> 6;
    if (lane == 0) { wx[wv] = ux; wy[wv] = uy; }
    __syncthreads();
    if (k0 == 0) {
        float sux = wx[0] + wx[1] + wx[2] + wx[3];
        float suy = wy[0] + wy[1] + wy[2] + wy[3];
        float2 vt = v[t];
        atomicAdd(&slots[16], vt.x * sux + vt.y * suy);   // num partial
        atomicAdd(&slots[17], vt.x * vt.x + vt.y * vt.y); // den partial
    }
}

__global__ void ray3_kernel(const float* __restrict__ slots, float* __restrict__ sc) {
    float step = slots[17] / slots[16];   // 1/lambda = den/num
    sc[0] = step;
    sc[1] = 0.1f * step;
}

// ---------------- qpack: M = I - step*Q  (identity folded onto diagonal)
// 2x4 micro-tile; c mapped as c0 + j*16 + tx (stride-1 float2 reads, 2-way free).
// 32-row m-tiles (25 KB LDS): halves barrier count vs 16-row version.
__global__ void qpack_kernel(const float* __restrict__ pr, const float* __restrict__ pi,
                             unsigned int* __restrict__ Bu, const float* __restrict__ sc) {
    __shared__ float2 Pn[32][33];
    __shared__ float2 Pc[32][65];
    float nstep = -sc[0];
    int t = threadIdx.x;
    int tx = t & 15, ty = t >> 4;
    int n0 = blockIdx.x * 32, c0 = blockIdx.y * 64;
    float2 q[2][4] = {};
    for (int m0 = 0; m0 < Mm; m0 += 32) {
        #pragma unroll
        for (int rep = 0; rep < 12; ++rep) {
            int idx = t + rep * 256;
            if (idx < 1024) {
                int mm = idx >> 5, col = idx & 31;
                int gm = m0 + mm;
                float2 a = make_float2(0.f, 0.f);
                if (gm < Mm && n0 + col < Nn)
                    a = make_float2(pr[(size_t)gm * Nn + n0 + col], pi[(size_t)gm * Nn + n0 + col]);
                Pn[mm][col] = a;
            } else {
                int idx2 = idx - 1024;
                int mm = idx2 >> 6, col = idx2 & 63;
                int gm = m0 + mm;
                float2 b = make_float2(0.f, 0.f);
                if (gm < Mm && c0 + col < Nn)
                    b = make_float2(pr[(size_t)gm * Nn + c0 + col], pi[(size_t)gm * Nn + c0 + col]);
                Pc[mm][col] = b;
            }
        }
        __syncthreads();
        #pragma unroll
        for (int mm = 0; mm < 32; ++mm) {
            float2 a0 = Pn[mm][ty * 2], a1 = Pn[mm][ty * 2 + 1];
            float2 b0 = Pc[mm][tx], b1 = Pc[mm][16 + tx];
            float2 b2 = Pc[mm][32 + tx], b3 = Pc[mm][48 + tx];
            // q += a * conj(b)
            #define QMAC(qq, aa, bb) \
                qq.x = fmaf(aa.x, bb.x, qq.x); qq.x = fmaf(aa.y, bb.y, qq.x); \
                qq.y = fmaf(aa.y, bb.x, qq.y); qq.y = fmaf(-aa.x, bb.y, qq.y);
            QMAC(q[0][0], a0, b0) QMAC(q[0][1], a0, b1) QMAC(q[0][2], a0, b2) QMAC(q[0][3], a0, b3)
            QMAC(q[1][0], a1, b0) QMAC(q[1][1], a1, b1) QMAC(q[1][2], a1, b2) QMAC(q[1][3], a1, b3)
            #undef QMAC
        }
        __syncthreads();
    }
    #pragma unroll
    for (int i = 0; i < 2; ++i) {
        int n = n0 + ty * 2 + i;
        #pragma unroll
        for (int j = 0; j < 4; ++j) {
            int c = c0 + j * 16 + tx;
            if (n < Nn && c < Nn) {
                // M = I - step*Q : identity folds onto the real diagonal
                float MR = fmaf(nstep, q[i][j].x, (n == c) ? 1.0f : 0.0f);
                float MI = nstep * q[i][j].y;
                unsigned short hR = f16bits(MR);
                unsigned short hI = f16bits(MI);
                unsigned short nhI = hI ^ 0x8000u;
                int jr = ((c >> 5) * 64) + (c & 31);
                Bu[swzB(jr, n)]      = (unsigned)hR | ((unsigned)nhI << 16);  // Re row
                Bu[swzB(jr + 32, n)] = (unsigned)hI | ((unsigned)hR << 16);   // Im row
            }
        }
    }
}

// ---------------- rpack: r -> f16 pairs in A2 layout (K=640) ----------------
__global__ void rpack_kernel(const float* __restrict__ rr, const float* __restrict__ ri,
                             unsigned int* __restrict__ rp16) {
    int b = blockIdx.x * 256 + threadIdx.x;
    int m = blockIdx.y;
    rp16[swzA2(b, m)] = (unsigned)f16bits(rr[(size_t)b * Mm + m]) |
                        ((unsigned)f16bits(ri[(size_t)b * Mm + m]) << 16);
}

// ---------------- ppack2: B2 = -step*conj(phi) pack, K=640 layout ----------------
__global__ void ppack2_kernel(const float* __restrict__ pr, const float* __restrict__ pi,
                              unsigned int* __restrict__ B2u, const float* __restrict__ sc) {
    int n = blockIdx.x * 256 + threadIdx.x;
    int m = blockIdx.y;
    if (n >= Nn) return;
    float s = sc[0];
    float xr = pr[(size_t)m * Nn + n], xi = pi[(size_t)m * Nn + n];
    unsigned short x = f16bits(-s * xr), y = f16bits(-s * xi);
    int jr2 = ((n >> 5) * 64) + (n & 31);
    B2u[swzB2(jr2, m)]      = (unsigned)x | ((unsigned)y << 16);
    B2u[swzB2(jr2 + 32, m)] = (unsigned)(y ^ 0x8000u) | ((unsigned)x << 16);
}

// ---------------- rphi_mfma: rph16 = f16(step * r * conj(phi)) AND w1 = shrink(rph) -----
// Fuses ISTA iteration 0 (w0 = 0 -> acc = 0 -> w1 = shrink(rph); bit-identical).
__global__ __launch_bounds__(256, 2) void rphi_mfma_kernel(
    const _Float16* __restrict__ rp16, const _Float16* __restrict__ B2,
    unsigned int* __restrict__ rph16, unsigned int* __restrict__ w1o,
    const float* __restrict__ sc) {
    __shared__ _Float16 As[8192];
    __shared__ _Float16 Bs[8192];
    int tid = threadIdx.x;
    int lane = tid & 63, wv = tid >> 6;
    int wm = wv & 1, wn = wv >> 1;
    int bblk = blockIdx.x, nblk = blockIdx.y;
    int l31 = lane & 31, lh = lane >> 5;

    f32x16 acc[2][2] = {};

    for (int kt = 0; kt < 10; ++kt) {
        #pragma unroll
        for (int c = 0; c < 4; ++c) {
            int u = c * 256 + tid;
            const char* ga = (const char*)rp16 + (((size_t)(bblk * 10 + kt)) * 1024 + u) * 16;
            load_lds16(ga, &As[(size_t)(c * 256 + wv * 64) * 8]);
            const char* gb = (const char*)B2 + (((size_t)(nblk * 10 + kt)) * 1024 + u) * 16;
            load_lds16(gb, &Bs[(size_t)(c * 256 + wv * 64) * 8]);
        }
        __syncthreads();
        #pragma unroll
        for (int s = 0; s < 4; ++s) {
            int kq = s * 2 + lh;
            f16x8 af[2], bfr[2];
            #pragma unroll
            for (int mt = 0; mt < 2; ++mt)
                af[mt] = *reinterpret_cast<const f16x8*>(
                    &As[(size_t)(kq * 128 + wm * 64 + mt * 32 + l31) * 8]);
            #pragma unroll
            for (int nt = 0; nt < 2; ++nt)
                bfr[nt] = *reinterpret_cast<const f16x8*>(
                    &Bs[(size_t)(kq * 128 + wn * 64 + nt * 32 + l31) * 8]);
            #pragma unroll
            for (int mt = 0; mt < 2; ++mt)
                #pragma unroll
                for (int nt = 0; nt < 2; ++nt)
                    acc[mt][nt] = __builtin_amdgcn_mfma_f32_32x32x16_f16(af[mt], bfr[nt], acc[mt][nt], 0, 0, 0);
        }
        __syncthreads();
    }

    float thr = sc[1];
    int b0 = bblk * 128;
    int c = nblk * 64 + wn * 32 + l31;
    #pragma unroll
    for (int mt = 0; mt < 2; ++mt) {
        #pragma unroll
        for (int reg = 0; reg < 16; ++reg) {
            int row = b0 + wm * 64 + mt * 32 + ((reg & 3) + 8 * (reg >> 2) + 4 * lh);
            unsigned int ru = (unsigned)f16bits(-acc[mt][0][reg]) |
                              ((unsigned)f16bits(-acc[mt][1][reg]) << 16);
            rph16[(size_t)row * NCP + c] = ru;
            // fused ISTA it=0: w1 = shrink(rph) on the f16-quantized value
            float zr = f16lo(ru);
            float zi = f16hi(ru);
            float mag = sqrtf(zr * zr + zi * zi);
            float nm = mag - thr;
            float f = (nm > 0.f) ? (nm / mag) : 0.f;
            w1o[swzA(row, c)] = (unsigned)f16bits(zr * f) | ((unsigned)f16bits(zi * f) << 16);
        }
    }
}

// ---------------- main ISTA iteration (ista13): triple-buffered pipeline ---------------
// r13 skeleton (512 thr, 8 waves 2m x 4n, tile 128x128, counted-vmcnt + raw barriers,
// 31 k-tiles, XCD-tiled remap) with 3 static LDS buffers (144 KB, 1 block/CU):
// two tiles stay in flight across each compute (vmcnt(12)), doubling the latency slack
// of the 2-buffer version. Epilogue waits vmcnt(6) only (tile 31's loads never waited:
// it is structural zeros and skipped). Same hazard proof as 2-buffer: compute(T)+barrier
// precedes the stage overwriting T; per-wave vmcnt + barrier => tile-kt landed for all.
// Bq packs (I - step*Q): epilogue z = acc + rph.
__global__ __launch_bounds__(512) void ista13_kernel(
    const _Float16* __restrict__ wfi, const _Float16* __restrict__ Bq,
    unsigned int* __restrict__ wfo,
    const unsigned int* __restrict__ rph16,
    const float* __restrict__ sc, float* __restrict__ out, int last) {
    __shared__ _Float16 As0[8192], As1[8192], As2[8192];            // A k-tile 3-buf
    __shared__ _Float16 Bs0[2][8192], Bs1[2][8192], Bs2[2][8192];   // B k-tile 3-buf
    int tid = threadIdx.x;
    int lane = tid & 63, wv = tid >> 6;          // wv 0..7
    int wm = wv >> 2, wn = wv & 3;               // wm: row half; wn: 32-col group 0..3
    int id = blockIdx.x;
    int x = id & 7;                              // XCD (round-robin dispatch)
    int n = id >> 3;                             // 0..31 within XCD
    int bblk = (x & 3) * 8 + (n & 7);            // 0..31 (128-row group) ; 8 per XCD
    int nb2  = (x >> 2) * 4 + (n >> 3);          // 0..7  (128-col group) ; 4 per XCD
    int l31 = lane & 31, lh = lane >> 5;
    int slab = wn >> 1, chg = wn & 1;            // B slab + 32-col group within slab

    f32x16 acc[2][2] = {};                       // [mt][nt: 0=Re,1=Im]

    const char* gA  = (const char*)wfi + (size_t)bblk * 32 * 1024 * 16;
    const char* gB0 = (const char*)Bq + (size_t)(nb2 * 2 + 0) * 32 * 1024 * 16;
    const char* gB1 = (const char*)Bq + (size_t)(nb2 * 2 + 1) * 32 * 1024 * 16;

    // stage one k-tile: A 1024 chunks + B 2x1024 chunks, 512 threads -> 6 loads/thread
    #define STAGE9(kt, Ad, Bd)                                                        \
        {                                                                             \
            _Float16* Ap = (Ad);                                                      \
            _Float16* Bp0 = &(Bd)[0][0];                                              \
            _Float16* Bp1 = &(Bd)[1][0];                                              \
            _Pragma("unroll")                                                         \
            for (int cc = 0; cc < 2; ++cc) {                                          \
                int u = cc * 512 + tid;                                               \
                size_t ldst = (size_t)(cc * 512 + wv * 64) * 8;                       \
                load_lds16(gA + ((size_t)(kt) * 1024 + u) * 16, &Ap[ldst]);           \
                load_lds16(gB0 + ((size_t)(kt) * 1024 + u) * 16, &Bp0[ldst]);         \
                load_lds16(gB1 + ((size_t)(kt) * 1024 + u) * 16, &Bp1[ldst]);         \
            }                                                                         \
        }

    #define COMPUTE9(Asrc, Bsrc)                                                      \
        {                                                                             \
            _Pragma("unroll")                                                         \
            for (int s = 0; s < 4; ++s) {                                             \
                int kq = s * 2 + lh;                                                  \
                f16x8 af[2], bf[2];                                                   \
                _Pragma("unroll")                                                     \
                for (int mt = 0; mt < 2; ++mt)                                        \
                    af[mt] = *reinterpret_cast<const f16x8*>(                         \
                        &(Asrc)[(size_t)(kq * 128 + wm * 64 + mt * 32 + l31) * 8]);   \
                _Pragma("unroll")                                                     \
                for (int nt = 0; nt < 2; ++nt)                                        \
                    bf[nt] = *reinterpret_cast<const f16x8*>(                         \
                        &(Bsrc)[slab][(size_t)(kq * 128 + chg * 64 + nt * 32 + l31) * 8]); \
                _Pragma("unroll")                                                     \
                for (int mt = 0; mt < 2; ++mt)                                        \
                    _Pragma("unroll")                                                 \
                    for (int nt = 0; nt < 2; ++nt)                                    \
                        acc[mt][nt] = __builtin_amdgcn_mfma_f32_32x32x16_f16(         \
                            af[mt], bf[nt], acc[mt][nt], 0, 0, 0);                    \
            }                                                                         \
        }

    STAGE9(0, As0, Bs0);
    STAGE9(1, As1, Bs1);
    for (int kt = 0; kt < 30; kt += 3) {
        STAGE9(kt + 2, As2, Bs2);
        asm volatile("s_waitcnt vmcnt(12)" ::: "memory");  // tile kt landed; kt+1,kt+2 in flight
        __builtin_amdgcn_s_barrier();
        COMPUTE9(As0, Bs0);
        __builtin_amdgcn_s_barrier();
        STAGE9(kt + 3, As0, Bs0);
        asm volatile("s_waitcnt vmcnt(12)" ::: "memory");  // tile kt+1 landed
        __builtin_amdgcn_s_barrier();
        COMPUTE9(As1, Bs1);
        __builtin_amdgcn_s_barrier();
        STAGE9(kt + 4, As1, Bs1);                          // max kt+4 = 31 (in bounds, zeros)
        asm volatile("s_waitcnt vmcnt(12)" ::: "memory");  // tile kt+2 landed
        __builtin_amdgcn_s_barrier();
        COMPUTE9(As2, Bs2);
        __builtin_amdgcn_s_barrier();
    }
    // tiles 0..29 computed; in flight: tile 30 (As0/Bs0, 6 loads) + tile 31 (As1/Bs1, 6)
    asm volatile("s_waitcnt vmcnt(6)" ::: "memory");       // tile 30 landed
    __builtin_amdgcn_s_barrier();
    COMPUTE9(As0, Bs0);
    // tile 31 skipped: structurally zero (w and Bq cols 992..1023 are padding zeros)
    #undef STAGE9
    #undef COMPUTE9

    float thr = sc[1];
    int b0 = bblk * 128;
    int c = nb2 * 128 + wn * 32 + l31;   // complex col for this lane
    #pragma unroll
    for (int mt = 0; mt < 2; ++mt) {
        #pragma unroll
        for (int reg = 0; reg < 16; ++reg) {
            int row = b0 + wm * 64 + mt * 32 + ((reg & 3) + 8 * (reg >> 2) + 4 * lh);
            unsigned int ru = rph16[(size_t)row * NCP + c];
            float zr = acc[mt][0][reg] + f16lo(ru);
            float zi = acc[mt][1][reg] + f16hi(ru);
            float mag = sqrtf(zr * zr + zi * zi);
            float nm = mag - thr;
            float f = (nm > 0.f) ? (nm / mag) : 0.f;
            wfo[swzA(row, c)] = (unsigned)f16bits(zr * f) | ((unsigned)f16bits(zi * f) << 16);
            if (last && c < Nn) out[(size_t)row * Nn + c] = fmaxf(nm, 0.f);
        }
    }
}

extern "C" void kernel_launch(void* const* d_in, const int* in_sizes, int n_in,
                              void* d_out, int out_size, void* d_ws, size_t ws_size,
                              hipStream_t stream) {
    const float* rr = (const float*)d_in[0];
    const float* ri = (const float*)d_in[1];
    const float* pr = (const float*)d_in[2];
    const float* pi = (const float*)d_in[3];
    float* out = (float*)d_out;

    char* ws = (char*)d_ws;
    size_t off = 0;
    _Float16* wf0 = (_Float16*)(ws + off); off += (size_t)Bb * KA * sizeof(_Float16);   // 16 MB
    _Float16* wf1 = (_Float16*)(ws + off); off += (size_t)Bb * KA * sizeof(_Float16);   // 16 MB
    _Float16* Bq  = (_Float16*)(ws + off); off += (size_t)2048 * 2048 * sizeof(_Float16); // 8 MB
    unsigned int* rph16 = (unsigned int*)(ws + off); off += (size_t)Bb * NCP * 4;       // 16 MB
    _Float16* rp16 = (_Float16*)(ws + off); off += (size_t)Bb * 640 * sizeof(_Float16);   // 5.2 MB
    _Float16* B2  = (_Float16*)(ws + off); off += (size_t)2048 * 640 * sizeof(_Float16);  // 2.6 MB
    float2* G = (float2*)(ws + off);     off += (size_t)Mm * Mm * sizeof(float2);
    float2* H1 = (float2*)(ws + off);    off += (size_t)Mm * Mm * sizeof(float2);
    float2* H2 = (float2*)(ws + off);    off += (size_t)Mm * Mm * sizeof(float2);
    float2* vvec = (float2*)(ws + off);  off += (size_t)Mm * sizeof(float2);
    float* slots = (float*)(ws + off);   off += 64 * sizeof(float);
    float* sc = slots + 32;

    // wf0 memset dropped: it=1 (first ista dispatch) writes wf0 before anything reads it
    (void)hipMemsetAsync(Bq, 0, (size_t)2048 * 2048 * sizeof(_Float16), stream);
    (void)hipMemsetAsync(rp16, 0, (size_t)Bb * 640 * sizeof(_Float16), stream);
    (void)hipMemsetAsync(B2, 0, (size_t)2048 * 640 * sizeof(_Float16), stream);
    (void)hipMemsetAsync(slots, 0, 64 * sizeof(float), stream);
    (void)hipMemsetAsync(G, 0, (size_t)Mm * Mm * sizeof(float2), stream);

    // spectral norm chain on G (306x306): G -> normalize+square x KSQ -> Rayleigh
    gram_kernel<<<dim3(10, 10, 4), dim3(16, 16), 0, stream>>>(pr, pi, G);
    float2* bufs[2] = { H1, H2 };
    const float2* src = G;
    for (int s = 0; s < KSQ; ++s) {
        float2* dst = bufs[s & 1];
        frobz_kernel<<<128, 256, 0, stream>>>(src, slots + s, dst, Mm * Mm);
        sqmm_kernel<<<dim3(10, 10, 4), dim3(16, 16), 0, stream>>>(src, dst, slots + s);
        src = dst;
    }
    ray1_kernel<<<Mm, 256, 0, stream>>>(src, vvec);
    ray2_kernel<<<Mm, 256, 0, stream>>>(G, vvec, slots);
    ray3_kernel<<<1, 1, 0, stream>>>(slots, sc);

    // precompute: packed operator (I - step*Q f16), r pack, -step*conj(phi) pack,
    // rphi MFMA (also produces w1 = shrink(rph), i.e. ISTA iteration 0)
    qpack_kernel<<<dim3(31, 16), 256, 0, stream>>>(pr, pi, (unsigned int*)Bq, sc);
    rpack_kernel<<<dim3(16, Mm), 256, 0, stream>>>(rr, ri, (unsigned int*)rp16);
    ppack2_kernel<<<dim3(4, Mm), 256, 0, stream>>>(pr, pi, (unsigned int*)B2, sc);
    rphi_mfma_kernel<<<dim3(32, 16), 256, 0, stream>>>(rp16, B2, rph16,
                                                       (unsigned int*)wf1, sc);

    // ISTA main loop: iterations 1..49 (it=0 fused into rphi), f16 state ping-pong
    _Float16* wbuf[2] = { wf0, wf1 };
    for (int it = 1; it < ITERS; ++it) {
        ista13_kernel<<<256, 512, 0, stream>>>(
            wbuf[it & 1], Bq, (unsigned int*)wbuf[(it + 1) & 1], rph16, sc, out,
            it == ITERS - 1 ? 1 : 0);
    }
}